// Round 5
// baseline (468.371 us; speedup 1.0000x reference)
//
#include <hip/hip_runtime.h>
#include <math.h>

// ---------- problem constants ----------
#define BB   8
#define NN   4096
#define CC   768
#define HH   12
#define DD   64
#define LL   64
#define BH   96          // BB*HH
#define MM_  32768       // BB*NN
#define KQKV 768
#define NQKV 2304
#define NTILES 24        // K / 32

typedef short bf16x8 __attribute__((ext_vector_type(8)));
typedef float f32x4  __attribute__((ext_vector_type(4)));

union U4 { unsigned long long ll; unsigned short s[4]; };

__device__ __forceinline__ unsigned short f2bf(float f) {
  union { float f; unsigned u; } v; v.f = f;
  return (unsigned short)((v.u + 0x7FFFu + ((v.u >> 16) & 1u)) >> 16);
}
__device__ __forceinline__ float bf2f(unsigned short h) {
  union { unsigned u; float f; } v; v.u = ((unsigned)h) << 16;
  return v.f;
}
__device__ __forceinline__ f32x4 fzero4() {
  f32x4 z; z[0] = 0.f; z[1] = 0.f; z[2] = 0.f; z[3] = 0.f; return z;
}
__device__ __forceinline__ void gload_lds16(const void* g, void* l) {
  __builtin_amdgcn_global_load_lds(
      (const __attribute__((address_space(1))) void*)g,
      (__attribute__((address_space(3))) void*)l, 16, 0, 0);
}

// ---------- elementwise fp32 -> bf16 ----------
__global__ void conv_bf16(const float* __restrict__ in, short* __restrict__ out, int n4) {
  int i = blockIdx.x * 256 + threadIdx.x;
  if (i >= n4) return;
  float4 v = ((const float4*)in)[i];
  U4 p; p.s[0] = f2bf(v.x); p.s[1] = f2bf(v.y); p.s[2] = f2bf(v.z); p.s[3] = f2bf(v.w);
  ((unsigned long long*)out)[i] = p.ll;
}

// ---------- transpose fp32[R][C] -> bf16[C][R] ----------
__global__ __launch_bounds__(256) void transpose_bf16(
    const float* __restrict__ in, short* __restrict__ out, int R, int C) {
  __shared__ float tile[32][33];
  int c0 = blockIdx.x * 32, r0 = blockIdx.y * 32;
  int tx = threadIdx.x & 31, ty = threadIdx.x >> 5;
  for (int i = ty; i < 32; i += 8)
    tile[i][tx] = in[(r0 + i) * C + c0 + tx];
  __syncthreads();
  for (int i = ty; i < 32; i += 8)
    out[(c0 + i) * R + r0 + tx] = (short)f2bf(tile[tx][i]);
}

// ---------- 256x256 bf16 MFMA GEMM, phased schedule (m201 skeleton), counted vmcnt ----------
// 4-slot ring (BK=32), prefetch distance 3. Per K-tile: 2 phases, each:
//   {ds_read frags ; issue 2 gload_lds ; barrier ; lgkmcnt(0) ; setprio(1) ;
//    16 MFMA ; setprio(0) ; [counted vmcnt] ; barrier}
// No sched_barrier(0) (m141 lesson). Counted vmcnt never 0 in steady state.
// EPI 0: qkv  (A=xb,  B=wqkvT)  -> Qb (scaled 1/8), Kb, Vb (all [bh][n][d])
// EPI 1: proj (A=SVb, B=wprojT) -> fout = acc + bias + V-residual (Vb)
// Both epilogues bounce through LDS with a 32B-granule XOR swizzle (conflict-free).
template <int EPI>
__global__ __launch_bounds__(512, 2) void gemm256(
    const short* __restrict__ A, const short* __restrict__ Bw,
    short* __restrict__ o0, short* __restrict__ o1, short* __restrict__ o2,
    const float* __restrict__ bias, float* __restrict__ fout) {
  __shared__ short L[65536];   // 128 KiB: slot s at s*32768 bytes (A 16KB | B 16KB)
  const int t = threadIdx.x;
  const int wave = t >> 6, lane = t & 63;
  const int wm = wave >> 2, wn = wave & 3;
  const int lrow = lane & 15, g = lane >> 4;

  // XCD-bijective block swizzle (gridDim.x % 8 == 0 for both uses)
  const int q8 = gridDim.x >> 3;
  const int wg = ((int)blockIdx.x & 7) * q8 + ((int)blockIdx.x >> 3);
  const int tm = wg & 127, tn = wg >> 7;
  const int m0 = tm << 8, n0 = tn << 8;

  // staging: thread stages 16B slots t*16 and t*16+8192 of each 16KB chunk.
  const int csl = (((t & 3) ^ ((t >> 3) & 3)) << 3);   // pre-swizzled source col
  const short* pA0 = A  + (size_t)(m0 + (t >> 2)) * KQKV + csl;
  const short* pA1 = pA0 + 128 * KQKV;
  const short* pB0 = Bw + (size_t)(n0 + (t >> 2)) * KQKV + csl;
  const short* pB1 = pB0 + 128 * KQKV;
  char* ldsA = (char*)L + wave * 1024;      // + slot*32768 (+8192 for rows 128..255)
  char* ldsB = ldsA + 16384;

  // fragment read addressing (swizzled): byte = r*64 + ((g ^ ((lrow>>1)&3))<<4)
  const int swz16 = ((g ^ ((lrow >> 1) & 3)) << 4);
  const int aoff = (wm * 128 + lrow) * 64 + swz16;            // + mh*4096 + m*1024
  const int boff = 16384 + (wn * 64 + lrow) * 64 + swz16;     // + nf*1024

  f32x4 acc[8][4];
#pragma unroll
  for (int i = 0; i < 8; ++i)
#pragma unroll
    for (int j = 0; j < 4; ++j) acc[i][j] = fzero4();

  // ---- prologue: stage tiles 0..2 ----
#pragma unroll
  for (int T = 0; T < 3; ++T) {
    gload_lds16(pA0 + T * 32, ldsA + T * 32768);
    gload_lds16(pA1 + T * 32, ldsA + T * 32768 + 8192);
    gload_lds16(pB0 + T * 32, ldsB + T * 32768);
    gload_lds16(pB1 + T * 32, ldsB + T * 32768 + 8192);
  }
  asm volatile("s_waitcnt vmcnt(8)" ::: "memory");
  __builtin_amdgcn_s_barrier();

  for (int T = 0; T < NTILES; ++T) {
    const char* Lb = (const char*)L + (T & 3) * 32768;
    const int Ts = T + 3;
    const int sb = (Ts & 3) * 32768;
    const bool st = (Ts < NTILES);
    bf16x8 b[4], a0[4], a1[4];
    // ================= phase 1: issue window =================
#pragma unroll
    for (int nf = 0; nf < 4; ++nf) b[nf] = *(const bf16x8*)(Lb + boff + nf * 1024);
#pragma unroll
    for (int m = 0; m < 4; ++m)  a0[m] = *(const bf16x8*)(Lb + aoff + m * 1024);
    if (st) {
      gload_lds16(pA0 + Ts * 32, ldsA + sb);
      gload_lds16(pA1 + Ts * 32, ldsA + sb + 8192);
    }
    __builtin_amdgcn_s_barrier();
    asm volatile("s_waitcnt lgkmcnt(0)" ::: "memory");
    __builtin_amdgcn_s_setprio(1);
#pragma unroll
    for (int m = 0; m < 4; ++m)
#pragma unroll
      for (int nf = 0; nf < 4; ++nf)
        acc[m][nf] = __builtin_amdgcn_mfma_f32_16x16x32_bf16(a0[m], b[nf], acc[m][nf], 0, 0, 0);
    __builtin_amdgcn_s_setprio(0);
    __builtin_amdgcn_s_barrier();
    // ================= phase 2 =================
#pragma unroll
    for (int m = 0; m < 4; ++m)  a1[m] = *(const bf16x8*)(Lb + aoff + 4096 + m * 1024);
    if (st) {
      gload_lds16(pB0 + Ts * 32, ldsB + sb);
      gload_lds16(pB1 + Ts * 32, ldsB + sb + 8192);
    }
    __builtin_amdgcn_s_barrier();
    asm volatile("s_waitcnt lgkmcnt(0)" ::: "memory");
    __builtin_amdgcn_s_setprio(1);
#pragma unroll
    for (int m = 0; m < 4; ++m)
#pragma unroll
      for (int nf = 0; nf < 4; ++nf)
        acc[4 + m][nf] = __builtin_amdgcn_mfma_f32_16x16x32_bf16(a1[m], b[nf], acc[4 + m][nf], 0, 0, 0);
    __builtin_amdgcn_s_setprio(0);
    // counted vmcnt: tile T+1 must have landed before the barrier releases readers
    if (T < NTILES - 3)       { asm volatile("s_waitcnt vmcnt(8)" ::: "memory"); }
    else if (T == NTILES - 3) { asm volatile("s_waitcnt vmcnt(4)" ::: "memory"); }
    else if (T == NTILES - 2) { asm volatile("s_waitcnt vmcnt(0)" ::: "memory"); }
    __builtin_amdgcn_s_barrier();
  }

  // ================= epilogue =================
  if constexpr (EPI == 0) {
    const int three = tn / 3;
    const int ccb = (tn % 3) * 256;
    short* dst = (three == 0) ? o0 : (three == 1) ? o1 : o2;
    const float sc = (three == 0) ? 0.125f : 1.f;
    // acc -> LDS bf16 [256][256] with 32B-granule XOR swizzle, then coalesced stores
    short* LS = (short*)L;
#pragma unroll
    for (int mf = 0; mf < 8; ++mf)
#pragma unroll
      for (int nf = 0; nf < 4; ++nf)
#pragma unroll
        for (int i = 0; i < 4; ++i) {
          int row = wm * 128 + mf * 16 + g * 4 + i;
          int col = wn * 64 + nf * 16 + lrow;
          int c32 = (col >> 4) ^ ((row >> 2) & 3);
          LS[row * 256 + (c32 << 4) + (col & 15)] = (short)f2bf(acc[mf][nf][i] * sc);
        }
    __syncthreads();
#pragma unroll
    for (int k = 0; k < 16; ++k) {
      int id = t + k * 512;
      int row = id >> 5, ch = id & 31;
      int c32 = (ch >> 1) ^ ((row >> 2) & 3);
      bf16x8 v = *(const bf16x8*)&LS[row * 256 + (c32 << 4) + ((ch & 1) << 3)];
      int c = ccb + ch * 8;
      int h = c >> 6, d = c & 63;
      int r = m0 + row;
      int bb = r >> 12, n = r & 4095;
      *(bf16x8*)&dst[((size_t)(bb * HH + h) * NN + n) * DD + d] = v;
    }
  } else {
    // LDS-bounce: two passes of 128 rows x 256 f32 = 128 KiB each, 32B-granule swizzle.
    float* LF = (float*)L;
#pragma unroll
    for (int pass = 0; pass < 2; ++pass) {
      if (wm == pass) {
#pragma unroll
        for (int mf = 0; mf < 8; ++mf)
#pragma unroll
          for (int nf = 0; nf < 4; ++nf)
#pragma unroll
            for (int i = 0; i < 4; ++i) {
              int row = mf * 16 + g * 4 + i;
              int col = wn * 64 + nf * 16 + lrow;
              int c8 = (col >> 3) ^ ((row >> 2) & 3);
              LF[row * 256 + (c8 << 3) + (col & 7)] = acc[mf][nf][i];
            }
      }
      __syncthreads();
#pragma unroll
      for (int k = 0; k < 16; ++k) {
        int id = t + k * 512;
        int row = id >> 6, ch = id & 63;
        int c8 = (ch >> 1) ^ ((row >> 2) & 3);
        float4 v = *(const float4*)&LF[row * 256 + (c8 << 3) + ((ch & 1) << 2)];
        int R = m0 + pass * 128 + row;
        int c = n0 + ch * 4;
        int bb2 = R >> 12, n = R & 4095, h = c >> 6, d = c & 63;
        float4 bi = *(const float4*)&bias[c];
        U4 r4;
        r4.ll = *(const unsigned long long*)&o2[((size_t)(bb2 * HH + h) * NN + n) * DD + d];
        v.x += bi.x + bf2f(r4.s[0]);
        v.y += bi.y + bf2f(r4.s[1]);
        v.z += bi.z + bf2f(r4.s[2]);
        v.w += bi.w + bf2f(r4.s[3]);
        *(float4*)&fout[(size_t)R * CC + c] = v;
      }
      __syncthreads();
    }
  }
}

// ---------- landmark means (coalesced bf16x8 + shfl reduce) ----------
__global__ __launch_bounds__(64) void landmarks(
    const short* __restrict__ Qb, const short* __restrict__ Kb,
    short* __restrict__ Qlmb, short* __restrict__ Klmb,
    float* __restrict__ QlmF, float* __restrict__ KlmF) {
  int bh = blockIdx.y, l = blockIdx.x, t = threadIdx.x;
  int rg = t >> 3, dg = t & 7;
  const short* qp = Qb + ((size_t)bh * NN + l * 64 + rg) * DD + dg * 8;
  const short* kp = Kb + ((size_t)bh * NN + l * 64 + rg) * DD + dg * 8;
  float sq[8], sk[8];
#pragma unroll
  for (int j = 0; j < 8; ++j) { sq[j] = 0.f; sk[j] = 0.f; }
  for (int s = 0; s < 8; ++s) {
    bf16x8 qv = *(const bf16x8*)(qp + (size_t)s * 8 * DD);
    bf16x8 kv = *(const bf16x8*)(kp + (size_t)s * 8 * DD);
#pragma unroll
    for (int j = 0; j < 8; ++j) {
      sq[j] += bf2f((unsigned short)qv[j]);
      sk[j] += bf2f((unsigned short)kv[j]);
    }
  }
#pragma unroll
  for (int j = 0; j < 8; ++j) {
    sq[j] += __shfl_xor(sq[j], 8); sq[j] += __shfl_xor(sq[j], 16); sq[j] += __shfl_xor(sq[j], 32);
    sk[j] += __shfl_xor(sk[j], 8); sk[j] += __shfl_xor(sk[j], 16); sk[j] += __shfl_xor(sk[j], 32);
  }
  if (t < 8) {
    int o = bh * 4096 + l * 64 + dg * 8;
#pragma unroll
    for (int j = 0; j < 8; ++j) {
      float q = sq[j] * (1.f / 64.f), k = sk[j] * (1.f / 64.f);
      Qlmb[o + j] = (short)f2bf(q); Klmb[o + j] = (short)f2bf(k);
      QlmF[o + j] = q; KlmF[o + j] = k;
    }
  }
}

// ---------- fused kernel3: logits+exp (in LDS) and PV partials, no P3 round-trip ----------
__global__ __launch_bounds__(256) void e12(
    const short* __restrict__ Kb, const short* __restrict__ Vb,
    const short* __restrict__ Qlmb,
    float* __restrict__ k3VTp, float* __restrict__ s3part) {
  int bh = blockIdx.y, chunk = blockIdx.x, n0 = chunk * 128;
  __shared__ short Qlm[64 * 72];
  __shared__ short Plds[64 * 136];
  __shared__ short Vl[128 * 68];
  int t = threadIdx.x;
  for (int r = 0; r < 2; r++) {
    int e = t + r * 256;
    *(bf16x8*)&Qlm[(e >> 3) * 72 + (e & 7) * 8] = *(const bf16x8*)&Qlmb[bh * 4096 + e * 8];
  }
#pragma unroll
  for (int r = 0; r < 4; r++) {
    int id = t + r * 256;
    int n = id >> 3, c8 = id & 7;
    U4 v;
    v.ll = *(const unsigned long long*)&Vb[((size_t)bh * NN + n0 + n) * DD + c8 * 8];
    unsigned long long v2 = *(const unsigned long long*)&Vb[((size_t)bh * NN + n0 + n) * DD + c8 * 8 + 4];
    *(unsigned long long*)&Vl[n * 68 + c8 * 8] = v.ll;
    *(unsigned long long*)&Vl[n * 68 + c8 * 8 + 4] = v2;
  }
  __syncthreads();
  int wave = t >> 6, lane = t & 63, lrow = lane & 15, g = lane >> 4, lk = g << 3;
  int nw = n0 + wave * 32;
  bf16x8 aK[2][2];
#pragma unroll
  for (int rf = 0; rf < 2; rf++)
#pragma unroll
    for (int ks = 0; ks < 2; ks++)
      aK[rf][ks] = *(const bf16x8*)&Kb[((size_t)bh * NN + nw + rf * 16 + lrow) * DD + ks * 32 + lk];
  f32x4 acc[2][4];
#pragma unroll
  for (int rf = 0; rf < 2; rf++)
#pragma unroll
    for (int lf = 0; lf < 4; lf++) acc[rf][lf] = fzero4();
#pragma unroll
  for (int ks = 0; ks < 2; ks++) {
    bf16x8 bq[4];
#pragma unroll
    for (int lf = 0; lf < 4; lf++)
      bq[lf] = *(const bf16x8*)&Qlm[(lf * 16 + lrow) * 72 + ks * 32 + lk];
#pragma unroll
    for (int rf = 0; rf < 2; rf++)
#pragma unroll
      for (int lf = 0; lf < 4; lf++)
        acc[rf][lf] = __builtin_amdgcn_mfma_f32_16x16x32_bf16(aK[rf][ks], bq[lf], acc[rf][lf], 0, 0, 0);
  }
#pragma unroll
  for (int lf = 0; lf < 4; lf++) {
    float cp = 0.f;
    int l = lf * 16 + lrow;
#pragma unroll
    for (int rf = 0; rf < 2; rf++) {
      U4 p;
#pragma unroll
      for (int i = 0; i < 4; i++) {
        float e = expf(acc[rf][lf][i]);   // logits tiny (sd~0.04): no max needed
        p.s[i] = f2bf(e); cp += e;
      }
      *(unsigned long long*)&Plds[l * 136 + wave * 32 + rf * 16 + g * 4] = p.ll;
    }
    cp += __shfl_xor(cp, 16);
    cp += __shfl_xor(cp, 32);
    if (lane < 16)
      s3part[((bh * 32 + chunk) * 4 + wave) * LL + lf * 16 + lane] = cp;
  }
  __syncthreads();
  f32x4 o2[4];
#pragma unroll
  for (int lf = 0; lf < 4; lf++) o2[lf] = fzero4();
  const int dloc = wave * 16 + lrow;
#pragma unroll
  for (int ks = 0; ks < 4; ++ks) {
    bf16x8 a;
#pragma unroll
    for (int j = 0; j < 8; ++j) a[j] = Vl[(ks * 32 + lk + j) * 68 + dloc];
#pragma unroll
    for (int lf = 0; lf < 4; lf++) {
      bf16x8 b = *(const bf16x8*)&Plds[(lf * 16 + lrow) * 136 + ks * 32 + lk];
      o2[lf] = __builtin_amdgcn_mfma_f32_16x16x32_bf16(a, b, o2[lf], 0, 0, 0);
    }
  }
#pragma unroll
  for (int lf = 0; lf < 4; lf++) {
    int l = lf * 16 + lrow;
#pragma unroll
    for (int i = 0; i < 4; i++) {
      int dd = wave * 16 + g * 4 + i;
      k3VTp[((size_t)chunk * BH + bh) * 4096 + dd * 64 + l] = o2[lf][i];
    }
  }
}

// ---------- per-(b,h): kernel2 softmax + Newton-Schulz inverse + M = inv @ k3V ----------
__device__ __forceinline__ void mm64(const float* X, const float* Y, int row, int c0, float o[8]) {
#pragma unroll
  for (int j = 0; j < 8; j++) o[j] = 0.f;
  for (int k = 0; k < 64; k++) {
    float x = X[row * 68 + k];
    const float4* yp = (const float4*)&Y[k * 68 + c0];
    float4 y0 = yp[0], y1 = yp[1];
    o[0] += x * y0.x; o[1] += x * y0.y; o[2] += x * y0.z; o[3] += x * y0.w;
    o[4] += x * y1.x; o[5] += x * y1.y; o[6] += x * y1.z; o[7] += x * y1.w;
  }
}

__global__ __launch_bounds__(512) void newton_inv(
    const float* __restrict__ QlmF, const float* __restrict__ KlmF,
    const float* __restrict__ k3VTp, const float* __restrict__ s3part,
    short* __restrict__ MTws) {
  __shared__ float A_[64 * 68], B_[64 * 68], C_[64 * 68], D_[64 * 68], E_[64 * 68];
  __shared__ float red[64];
  __shared__ float denom_s;
  int bh = blockIdx.x, t = threadIdx.x;
  int row = t >> 3, c0 = (t & 7) << 3;
#pragma unroll
  for (int i = 0; i < 8; i++) {
    int e = t * 8 + i;
    A_[(e >> 6) * 68 + (e & 63)] = QlmF[bh * 4096 + e];
    B_[(e >> 6) * 68 + (e & 63)] = KlmF[bh * 4096 + e];
  }
  __syncthreads();
  {  // S2 = Qlm @ Klm^T ; softmax rows -> C_
    float4 ar[16];
#pragma unroll
    for (int q = 0; q < 16; q++) ar[q] = *(const float4*)&A_[row * 68 + q * 4];
    float o[8];
#pragma unroll
    for (int mm = 0; mm < 8; mm++) {
      const float4* br = (const float4*)&B_[(c0 + mm) * 68];
      float s = 0.f;
      for (int q = 0; q < 16; q++) {
        float4 b4 = br[q];
        s += ar[q].x * b4.x + ar[q].y * b4.y + ar[q].z * b4.z + ar[q].w * b4.w;
      }
      o[mm] = s;
    }
    float mx = o[0];
#pragma unroll
    for (int mm = 1; mm < 8; mm++) mx = fmaxf(mx, o[mm]);
    mx = fmaxf(mx, __shfl_xor(mx, 1));
    mx = fmaxf(mx, __shfl_xor(mx, 2));
    mx = fmaxf(mx, __shfl_xor(mx, 4));
    float ss = 0.f;
#pragma unroll
    for (int mm = 0; mm < 8; mm++) { o[mm] = expf(o[mm] - mx); ss += o[mm]; }
    ss += __shfl_xor(ss, 1); ss += __shfl_xor(ss, 2); ss += __shfl_xor(ss, 4);
    float r = 1.f / ss;
#pragma unroll
    for (int mm = 0; mm < 8; mm++) C_[row * 68 + c0 + mm] = o[mm] * r;
  }
  __syncthreads();
  if (t < 64) {
    float s = 0.f;
    for (int l2 = 0; l2 < 64; l2++) s += C_[l2 * 68 + t];
    red[t] = s;
  }
  __syncthreads();
  if (t == 0) {
    float m = red[0];
    for (int i = 1; i < 64; i++) m = fmaxf(m, red[i]);
    denom_s = m;
  }
  __syncthreads();
  {
    float rdn = 1.f / denom_s;
#pragma unroll
    for (int i = 0; i < 8; i++) D_[row * 68 + c0 + i] = C_[(c0 + i) * 68 + row] * rdn;
  }
  __syncthreads();
  float* Vc = D_;
  float* t1 = A_;
  float* t2 = B_;
  float* t3 = E_;
  float o[8];
  for (int it = 0; it < 6; it++) {
    mm64(C_, Vc, row, c0, o);                       // KV
#pragma unroll
    for (int j = 0; j < 8; j++) t1[row * 68 + c0 + j] = o[j];
    __syncthreads();
    mm64(t1, t1, row, c0, o);                       // KV@KV
#pragma unroll
    for (int j = 0; j < 8; j++) t2[row * 68 + c0 + j] = 7.f * t1[row * 68 + c0 + j] - o[j];
    __syncthreads();
    mm64(t1, t2, row, c0, o);                       // KV@(7I-KV)
#pragma unroll
    for (int j = 0; j < 8; j++) t3[row * 68 + c0 + j] = 15.f * t1[row * 68 + c0 + j] - o[j];
    __syncthreads();
    mm64(Vc, t3, row, c0, o);                       // V@(13I - T3)
#pragma unroll
    for (int j = 0; j < 8; j++) t2[row * 68 + c0 + j] = 0.25f * (13.f * Vc[row * 68 + c0 + j] - o[j]);
    __syncthreads();
    float* tmp = Vc; Vc = t2; t2 = tmp;
  }
  if (t < 64) {
    float s = 0.f;
    for (int i2 = 0; i2 < 128; i2++) s += s3part[(bh * 128 + i2) * LL + t];
    red[t] = 1.f / s;
  }
  __syncthreads();
#pragma unroll
  for (int i = 0; i < 8; i++) {
    int e = t * 8 + i;
    float s = 0.f;
    for (int c = 0; c < 32; c++) s += k3VTp[((size_t)c * BH + bh) * 4096 + e];
    t1[(e >> 6) * 68 + (e & 63)] = s * red[e & 63];
  }
  __syncthreads();
  {
    float4 ar[16];
#pragma unroll
    for (int q = 0; q < 16; q++) ar[q] = *(const float4*)&t1[row * 68 + q * 4];
    for (int jj = 0; jj < 8; jj++) {
      const float4* dr = (const float4*)&Vc[(c0 + jj) * 68];
      float s = 0.f;
      for (int q = 0; q < 16; q++) {
        float4 d4 = dr[q];
        s += ar[q].x * d4.x + ar[q].y * d4.y + ar[q].z * d4.z + ar[q].w * d4.w;
      }
      MTws[bh * 4096 + row * 64 + c0 + jj] = (short)f2bf(s);
    }
  }
}

// ---------- kernel1 softmax + @M  -> SV (in [B,N,C] bf16) ----------
__global__ __launch_bounds__(256) void pass2(
    const short* __restrict__ Qb, const short* __restrict__ Klmb,
    const short* __restrict__ MTws, short* __restrict__ SVb) {
  int bh = blockIdx.y, n0 = blockIdx.x * 128;
  int bb = bh / HH, hh = bh % HH;
  __shared__ short Klm[64 * 72];
  __shared__ short Mt[64 * 72];
  __shared__ short Pl[128 * 72];
  int t = threadIdx.x;
  for (int r = 0; r < 2; r++) {
    int e = t + r * 256;
    *(bf16x8*)&Klm[(e >> 3) * 72 + (e & 7) * 8] = *(const bf16x8*)&Klmb[bh * 4096 + e * 8];
    *(bf16x8*)&Mt[(e >> 3) * 72 + (e & 7) * 8]  = *(const bf16x8*)&MTws[bh * 4096 + e * 8];
  }
  __syncthreads();
  int wave = t >> 6, lane = t & 63, lrow = lane & 15, lk = (lane >> 4) << 3;
  int nw = wave * 32;
  bf16x8 aQ[2][2];
#pragma unroll
  for (int rf = 0; rf < 2; rf++)
#pragma unroll
    for (int ks = 0; ks < 2; ks++)
      aQ[rf][ks] = *(const bf16x8*)&Qb[((size_t)bh * NN + n0 + nw + rf * 16 + lrow) * DD + ks * 32 + lk];
  f32x4 s[2][4];
#pragma unroll
  for (int rf = 0; rf < 2; rf++)
#pragma unroll
    for (int jf = 0; jf < 4; jf++) s[rf][jf] = fzero4();
#pragma unroll
  for (int ks = 0; ks < 2; ks++) {
    bf16x8 bk[4];
#pragma unroll
    for (int jf = 0; jf < 4; jf++)
      bk[jf] = *(const bf16x8*)&Klm[(jf * 16 + lrow) * 72 + ks * 32 + lk];
#pragma unroll
    for (int rf = 0; rf < 2; rf++)
#pragma unroll
      for (int jf = 0; jf < 4; jf++)
        s[rf][jf] = __builtin_amdgcn_mfma_f32_16x16x32_bf16(aQ[rf][ks], bk[jf], s[rf][jf], 0, 0, 0);
  }
#pragma unroll
  for (int rf = 0; rf < 2; rf++)
#pragma unroll
    for (int i = 0; i < 4; i++) {
      float v0 = s[rf][0][i], v1 = s[rf][1][i], v2 = s[rf][2][i], v3 = s[rf][3][i];
      float mx = fmaxf(fmaxf(v0, v1), fmaxf(v2, v3));
      mx = fmaxf(mx, __shfl_xor(mx, 1));
      mx = fmaxf(mx, __shfl_xor(mx, 2));
      mx = fmaxf(mx, __shfl_xor(mx, 4));
      mx = fmaxf(mx, __shfl_xor(mx, 8));
      v0 = expf(v0 - mx); v1 = expf(v1 - mx); v2 = expf(v2 - mx); v3 = expf(v3 - mx);
      float ss = v0 + v1 + v2 + v3;
      ss += __shfl_xor(ss, 1); ss += __shfl_xor(ss, 2);
      ss += __shfl_xor(ss, 4); ss += __shfl_xor(ss, 8);
      float rr = 1.f / ss;
      int n = nw + rf * 16 + ((lane >> 4) << 2) + i;
      Pl[n * 72 + 0  + lrow] = (short)f2bf(v0 * rr);
      Pl[n * 72 + 16 + lrow] = (short)f2bf(v1 * rr);
      Pl[n * 72 + 32 + lrow] = (short)f2bf(v2 * rr);
      Pl[n * 72 + 48 + lrow] = (short)f2bf(v3 * rr);
    }
  __syncthreads();
  f32x4 o[2][4];
#pragma unroll
  for (int rf = 0; rf < 2; rf++)
#pragma unroll
    for (int df = 0; df < 4; df++) o[rf][df] = fzero4();
#pragma unroll
  for (int ks = 0; ks < 2; ks++) {
    bf16x8 aP[2];
#pragma unroll
    for (int rf = 0; rf < 2; rf++)
      aP[rf] = *(const bf16x8*)&Pl[(nw + rf * 16 + lrow) * 72 + ks * 32 + lk];
    bf16x8 bm[4];
#pragma unroll
    for (int df = 0; df < 4; df++)
      bm[df] = *(const bf16x8*)&Mt[(df * 16 + lrow) * 72 + ks * 32 + lk];
#pragma unroll
    for (int rf = 0; rf < 2; rf++)
#pragma unroll
      for (int df = 0; df < 4; df++)
        o[rf][df] = __builtin_amdgcn_mfma_f32_16x16x32_bf16(aP[rf], bm[df], o[rf][df], 0, 0, 0);
  }
#pragma unroll
  for (int rf = 0; rf < 2; rf++)
#pragma unroll
    for (int df = 0; df < 4; df++)
#pragma unroll
      for (int i = 0; i < 4; i++) {
        int n = n0 + nw + rf * 16 + ((lane >> 4) << 2) + i;
        SVb[((size_t)bb * NN + n) * CC + hh * 64 + df * 16 + lrow] = (short)f2bf(o[rf][df][i]);
      }
}

extern "C" void kernel_launch(void* const* d_in, const int* in_sizes, int n_in,
                              void* d_out, int out_size, void* d_ws, size_t ws_size,
                              hipStream_t stream) {
  const float* x      = (const float*)d_in[0];
  const float* w_qkv  = (const float*)d_in[1];
  const float* w_proj = (const float*)d_in[2];
  const float* b_proj = (const float*)d_in[3];
  float* out = (float*)d_out;

  char* p = (char*)d_ws;
  auto alloc = [&](size_t bytes) -> char* {
    char* r = p; p += (bytes + 255) & ~(size_t)255; return r;
  };
  short* xb     = (short*)alloc((size_t)MM_ * KQKV * 2);
  short* wqkvT  = (short*)alloc((size_t)NQKV * KQKV * 2);
  short* wprojT = (short*)alloc((size_t)CC * CC * 2);
  short* Qb     = (short*)alloc((size_t)BH * NN * DD * 2);
  short* Kb     = (short*)alloc((size_t)BH * NN * DD * 2);
  short* Vb     = (short*)alloc((size_t)BH * NN * DD * 2);
  short* Qlmb   = (short*)alloc((size_t)BH * LL * DD * 2);
  short* Klmb   = (short*)alloc((size_t)BH * LL * DD * 2);
  float* QlmF   = (float*)alloc((size_t)BH * LL * DD * 4);
  float* KlmF   = (float*)alloc((size_t)BH * LL * DD * 4);
  float* s3part = (float*)alloc((size_t)BH * 128 * LL * 4);
  float* k3VTp  = (float*)alloc((size_t)32 * BH * DD * LL * 4);
  short* MTws   = (short*)alloc((size_t)BH * DD * LL * 2);
  short* SVb    = (short*)alloc((size_t)MM_ * CC * 2);

  conv_bf16<<<(MM_ * KQKV / 4 + 255) / 256, 256, 0, stream>>>(x, xb, MM_ * KQKV / 4);
  transpose_bf16<<<dim3(NQKV / 32, KQKV / 32), 256, 0, stream>>>(w_qkv, wqkvT, KQKV, NQKV);
  transpose_bf16<<<dim3(CC / 32, CC / 32), 256, 0, stream>>>(w_proj, wprojT, CC, CC);
  gemm256<0><<<dim3((MM_ / 256) * (NQKV / 256)), 512, 0, stream>>>(
      xb, wqkvT, Qb, Kb, Vb, nullptr, nullptr);
  landmarks<<<dim3(LL, BH), 64, 0, stream>>>(Qb, Kb, Qlmb, Klmb, QlmF, KlmF);
  e12<<<dim3(NN / 128, BH), 256, 0, stream>>>(Kb, Vb, Qlmb, k3VTp, s3part);
  newton_inv<<<BH, 512, 0, stream>>>(QlmF, KlmF, k3VTp, s3part, MTws);
  pass2<<<dim3(NN / 128, BH), 256, 0, stream>>>(Qb, Klmb, MTws, SVb);
  gemm256<1><<<dim3((MM_ / 256) * (CC / 256)), 512, 0, stream>>>(
      SVb, wprojT, nullptr, nullptr, Vb, b_proj, out);
}

// Round 6
// 455.211 us; speedup vs baseline: 1.0289x; 1.0289x over previous
//
#include <hip/hip_runtime.h>
#include <math.h>

// ---------- problem constants ----------
#define BB   8
#define NN   4096
#define CC   768
#define HH   12
#define DD   64
#define LL   64
#define BH   96          // BB*HH
#define MM_  32768       // BB*NN
#define KQKV 768
#define NQKV 2304
#define NTILES 24        // K / 32

typedef short bf16x8 __attribute__((ext_vector_type(8)));
typedef float f32x4  __attribute__((ext_vector_type(4)));

union U4 { unsigned long long ll; unsigned short s[4]; };

__device__ __forceinline__ unsigned short f2bf(float f) {
  union { float f; unsigned u; } v; v.f = f;
  return (unsigned short)((v.u + 0x7FFFu + ((v.u >> 16) & 1u)) >> 16);
}
__device__ __forceinline__ float bf2f(unsigned short h) {
  union { unsigned u; float f; } v; v.u = ((unsigned)h) << 16;
  return v.f;
}
__device__ __forceinline__ f32x4 fzero4() {
  f32x4 z; z[0] = 0.f; z[1] = 0.f; z[2] = 0.f; z[3] = 0.f; return z;
}
__device__ __forceinline__ void gload_lds16(const void* g, void* l) {
  __builtin_amdgcn_global_load_lds(
      (const __attribute__((address_space(1))) void*)g,
      (__attribute__((address_space(3))) void*)l, 16, 0, 0);
}

// ---------- elementwise fp32 -> bf16 ----------
__global__ void conv_bf16(const float* __restrict__ in, short* __restrict__ out, int n4) {
  int i = blockIdx.x * 256 + threadIdx.x;
  if (i >= n4) return;
  float4 v = ((const float4*)in)[i];
  U4 p; p.s[0] = f2bf(v.x); p.s[1] = f2bf(v.y); p.s[2] = f2bf(v.z); p.s[3] = f2bf(v.w);
  ((unsigned long long*)out)[i] = p.ll;
}

// ---------- transpose fp32[R][C] -> bf16[C][R] ----------
__global__ __launch_bounds__(256) void transpose_bf16(
    const float* __restrict__ in, short* __restrict__ out, int R, int C) {
  __shared__ float tile[32][33];
  int c0 = blockIdx.x * 32, r0 = blockIdx.y * 32;
  int tx = threadIdx.x & 31, ty = threadIdx.x >> 5;
  for (int i = ty; i < 32; i += 8)
    tile[i][tx] = in[(r0 + i) * C + c0 + tx];
  __syncthreads();
  for (int i = ty; i < 32; i += 8)
    out[(c0 + i) * R + r0 + tx] = (short)f2bf(tile[tx][i]);
}

// ---------- 256x256 bf16 MFMA GEMM, register-pipelined K-loop ----------
// 4-slot LDS ring (BK=32), gload prefetch distance 3, vmcnt(4) at tile end
// => tiles T+1 AND T+2 guaranteed in LDS at each barrier, so frags(T+1) are
// ds_read into a second register set WHILE tile T's MFMAs run (true overlap).
// One barrier + one lgkmcnt(0) per K-tile.
// EPI 0: qkv  -> Qb (scaled 1/8), Kb, Vb (all [bh][n][d])
// EPI 1: proj -> fout = acc + bias + V-residual (Vb)
template <int EPI>
__global__ __launch_bounds__(512, 2) void gemm256(
    const short* __restrict__ A, const short* __restrict__ Bw,
    short* __restrict__ o0, short* __restrict__ o1, short* __restrict__ o2,
    const float* __restrict__ bias, float* __restrict__ fout) {
  __shared__ short L[65536];   // 128 KiB: slot s at s*32768 bytes (A 16KB | B 16KB)
  const int t = threadIdx.x;
  const int wave = t >> 6, lane = t & 63;
  const int wm = wave >> 2, wn = wave & 3;
  const int lrow = lane & 15, g = lane >> 4;

  // XCD-bijective block swizzle (gridDim.x % 8 == 0 for both uses)
  const int q8 = gridDim.x >> 3;
  const int wg = ((int)blockIdx.x & 7) * q8 + ((int)blockIdx.x >> 3);
  const int tm = wg & 127, tn = wg >> 7;
  const int m0 = tm << 8, n0 = tn << 8;

  const int csl = (((t & 3) ^ ((t >> 3) & 3)) << 3);   // pre-swizzled source col
  const short* pA0 = A  + (size_t)(m0 + (t >> 2)) * KQKV + csl;
  const short* pA1 = pA0 + 128 * KQKV;
  const short* pB0 = Bw + (size_t)(n0 + (t >> 2)) * KQKV + csl;
  const short* pB1 = pB0 + 128 * KQKV;
  char* ldsA = (char*)L + wave * 1024;      // + slot*32768 (+8192 for rows 128..255)
  char* ldsB = ldsA + 16384;

  // fragment read addressing (swizzled): byte = r*64 + ((g ^ ((lrow>>1)&3))<<4)
  const int swz16 = ((g ^ ((lrow >> 1) & 3)) << 4);
  const int aoff = (wm * 128 + lrow) * 64 + swz16;            // + (m>>2)*4096 + (m&3)*1024
  const int boff = 16384 + (wn * 64 + lrow) * 64 + swz16;     // + nf*1024

  f32x4 acc[8][4];
#pragma unroll
  for (int i = 0; i < 8; ++i)
#pragma unroll
    for (int j = 0; j < 4; ++j) acc[i][j] = fzero4();

  bf16x8 aX[8], bX[4], aY[8], bY[4];

  // ---- prologue: stage tiles 0..2; tiles 0,1 landed; read frags(0) ----
#pragma unroll
  for (int T = 0; T < 3; ++T) {
    gload_lds16(pA0 + T * 32, ldsA + T * 32768);
    gload_lds16(pA1 + T * 32, ldsA + T * 32768 + 8192);
    gload_lds16(pB0 + T * 32, ldsB + T * 32768);
    gload_lds16(pB1 + T * 32, ldsB + T * 32768 + 8192);
  }
  asm volatile("s_waitcnt vmcnt(4)" ::: "memory");
  __builtin_amdgcn_s_barrier();
#pragma unroll
  for (int nf = 0; nf < 4; ++nf) bX[nf] = *(const bf16x8*)((const char*)L + boff + nf * 1024);
#pragma unroll
  for (int m = 0; m < 8; ++m)
    aX[m] = *(const bf16x8*)((const char*)L + aoff + (m >> 2) * 4096 + (m & 3) * 1024);
  asm volatile("s_waitcnt lgkmcnt(0)" ::: "memory");

  auto body = [&](int T, bf16x8 (&AC)[8], bf16x8 (&BC)[4],
                  bf16x8 (&AN)[8], bf16x8 (&BN)[4]) {
    const int Ts = T + 3;
    if (Ts < NTILES) {
      const int sb = (Ts & 3) * 32768;
      gload_lds16(pA0 + Ts * 32, ldsA + sb);
      gload_lds16(pA1 + Ts * 32, ldsA + sb + 8192);
      gload_lds16(pB0 + Ts * 32, ldsB + sb);
      gload_lds16(pB1 + Ts * 32, ldsB + sb + 8192);
    }
    __builtin_amdgcn_s_setprio(1);
#pragma unroll
    for (int m = 0; m < 4; ++m)
#pragma unroll
      for (int nf = 0; nf < 4; ++nf)
        acc[m][nf] = __builtin_amdgcn_mfma_f32_16x16x32_bf16(AC[m], BC[nf], acc[m][nf], 0, 0, 0);
    __builtin_amdgcn_s_setprio(0);
    if (T + 1 < NTILES) {   // read next tile's frags (landed: vmcnt(4)+barrier invariant)
      const char* Ln = (const char*)L + ((T + 1) & 3) * 32768;
#pragma unroll
      for (int nf = 0; nf < 4; ++nf) BN[nf] = *(const bf16x8*)(Ln + boff + nf * 1024);
#pragma unroll
      for (int m = 0; m < 8; ++m)
        AN[m] = *(const bf16x8*)(Ln + aoff + (m >> 2) * 4096 + (m & 3) * 1024);
    }
    __builtin_amdgcn_s_setprio(1);
#pragma unroll
    for (int m = 0; m < 4; ++m)
#pragma unroll
      for (int nf = 0; nf < 4; ++nf)
        acc[4 + m][nf] = __builtin_amdgcn_mfma_f32_16x16x32_bf16(AC[4 + m], BC[nf], acc[4 + m][nf], 0, 0, 0);
    __builtin_amdgcn_s_setprio(0);
    // tile-end: guarantee tiles T+1 (for next body's MFMA src regs already read)
    // and T+2 (for next body's frag reads) are in LDS across all waves.
    if (T < NTILES - 3)       { asm volatile("s_waitcnt vmcnt(4)" ::: "memory"); }
    else if (T == NTILES - 3) { asm volatile("s_waitcnt vmcnt(0)" ::: "memory"); }
    asm volatile("s_waitcnt lgkmcnt(0)" ::: "memory");
    __builtin_amdgcn_s_barrier();
  };

  for (int T = 0; T < NTILES; T += 2) {
    body(T, aX, bX, aY, bY);
    body(T + 1, aY, bY, aX, bX);
  }

  // ================= epilogue =================
  if constexpr (EPI == 0) {
    const int three = tn / 3;
    const int ccb = (tn % 3) * 256;
    short* dst = (three == 0) ? o0 : (three == 1) ? o1 : o2;
    const float sc = (three == 0) ? 0.125f : 1.f;
    short* LS = (short*)L;
#pragma unroll
    for (int mf = 0; mf < 8; ++mf)
#pragma unroll
      for (int nf = 0; nf < 4; ++nf)
#pragma unroll
        for (int i = 0; i < 4; ++i) {
          int row = wm * 128 + mf * 16 + g * 4 + i;
          int col = wn * 64 + nf * 16 + lrow;
          int c32 = (col >> 4) ^ ((row >> 2) & 3);
          LS[row * 256 + (c32 << 4) + (col & 15)] = (short)f2bf(acc[mf][nf][i] * sc);
        }
    __syncthreads();
#pragma unroll
    for (int k = 0; k < 16; ++k) {
      int id = t + k * 512;
      int row = id >> 5, ch = id & 31;
      int c32 = (ch >> 1) ^ ((row >> 2) & 3);
      bf16x8 v = *(const bf16x8*)&LS[row * 256 + (c32 << 4) + ((ch & 1) << 3)];
      int c = ccb + ch * 8;
      int h = c >> 6, d = c & 63;
      int r = m0 + row;
      int bb = r >> 12, n = r & 4095;
      *(bf16x8*)&dst[((size_t)(bb * HH + h) * NN + n) * DD + d] = v;
    }
  } else {
    float* LF = (float*)L;
#pragma unroll
    for (int pass = 0; pass < 2; ++pass) {
      if (wm == pass) {
#pragma unroll
        for (int mf = 0; mf < 8; ++mf)
#pragma unroll
          for (int nf = 0; nf < 4; ++nf)
#pragma unroll
            for (int i = 0; i < 4; ++i) {
              int row = mf * 16 + g * 4 + i;
              int col = wn * 64 + nf * 16 + lrow;
              int c8 = (col >> 3) ^ ((row >> 2) & 3);
              LF[row * 256 + (c8 << 3) + (col & 7)] = acc[mf][nf][i];
            }
      }
      __syncthreads();
#pragma unroll
      for (int k = 0; k < 16; ++k) {
        int id = t + k * 512;
        int row = id >> 6, ch = id & 63;
        int c8 = (ch >> 1) ^ ((row >> 2) & 3);
        float4 v = *(const float4*)&LF[row * 256 + (c8 << 3) + ((ch & 1) << 2)];
        int R = m0 + pass * 128 + row;
        int c = n0 + ch * 4;
        int bb2 = R >> 12, n = R & 4095, h = c >> 6, d = c & 63;
        float4 bi = *(const float4*)&bias[c];
        U4 r4;
        r4.ll = *(const unsigned long long*)&o2[((size_t)(bb2 * HH + h) * NN + n) * DD + d];
        v.x += bi.x + bf2f(r4.s[0]);
        v.y += bi.y + bf2f(r4.s[1]);
        v.z += bi.z + bf2f(r4.s[2]);
        v.w += bi.w + bf2f(r4.s[3]);
        *(float4*)&fout[(size_t)R * CC + c] = v;
      }
      __syncthreads();
    }
  }
}

// ---------- landmark means (coalesced bf16x8 + shfl reduce) ----------
__global__ __launch_bounds__(64) void landmarks(
    const short* __restrict__ Qb, const short* __restrict__ Kb,
    short* __restrict__ Qlmb, short* __restrict__ Klmb,
    float* __restrict__ QlmF, float* __restrict__ KlmF) {
  int bh = blockIdx.y, l = blockIdx.x, t = threadIdx.x;
  int rg = t >> 3, dg = t & 7;
  const short* qp = Qb + ((size_t)bh * NN + l * 64 + rg) * DD + dg * 8;
  const short* kp = Kb + ((size_t)bh * NN + l * 64 + rg) * DD + dg * 8;
  float sq[8], sk[8];
#pragma unroll
  for (int j = 0; j < 8; ++j) { sq[j] = 0.f; sk[j] = 0.f; }
  for (int s = 0; s < 8; ++s) {
    bf16x8 qv = *(const bf16x8*)(qp + (size_t)s * 8 * DD);
    bf16x8 kv = *(const bf16x8*)(kp + (size_t)s * 8 * DD);
#pragma unroll
    for (int j = 0; j < 8; ++j) {
      sq[j] += bf2f((unsigned short)qv[j]);
      sk[j] += bf2f((unsigned short)kv[j]);
    }
  }
#pragma unroll
  for (int j = 0; j < 8; ++j) {
    sq[j] += __shfl_xor(sq[j], 8); sq[j] += __shfl_xor(sq[j], 16); sq[j] += __shfl_xor(sq[j], 32);
    sk[j] += __shfl_xor(sk[j], 8); sk[j] += __shfl_xor(sk[j], 16); sk[j] += __shfl_xor(sk[j], 32);
  }
  if (t < 8) {
    int o = bh * 4096 + l * 64 + dg * 8;
#pragma unroll
    for (int j = 0; j < 8; ++j) {
      float q = sq[j] * (1.f / 64.f), k = sk[j] * (1.f / 64.f);
      Qlmb[o + j] = (short)f2bf(q); Klmb[o + j] = (short)f2bf(k);
      QlmF[o + j] = q; KlmF[o + j] = k;
    }
  }
}

// ---------- fused kernel3: logits+exp (in LDS) and PV partials ----------
__global__ __launch_bounds__(256) void e12(
    const short* __restrict__ Kb, const short* __restrict__ Vb,
    const short* __restrict__ Qlmb,
    float* __restrict__ k3VTp, float* __restrict__ s3part) {
  int bh = blockIdx.y, chunk = blockIdx.x, n0 = chunk * 128;
  __shared__ short Qlm[64 * 72];
  __shared__ short Plds[64 * 136];
  __shared__ short Vl[128 * 68];
  int t = threadIdx.x;
  for (int r = 0; r < 2; r++) {
    int e = t + r * 256;
    *(bf16x8*)&Qlm[(e >> 3) * 72 + (e & 7) * 8] = *(const bf16x8*)&Qlmb[bh * 4096 + e * 8];
  }
#pragma unroll
  for (int r = 0; r < 4; r++) {
    int id = t + r * 256;
    int n = id >> 3, c8 = id & 7;
    U4 v;
    v.ll = *(const unsigned long long*)&Vb[((size_t)bh * NN + n0 + n) * DD + c8 * 8];
    unsigned long long v2 = *(const unsigned long long*)&Vb[((size_t)bh * NN + n0 + n) * DD + c8 * 8 + 4];
    *(unsigned long long*)&Vl[n * 68 + c8 * 8] = v.ll;
    *(unsigned long long*)&Vl[n * 68 + c8 * 8 + 4] = v2;
  }
  __syncthreads();
  int wave = t >> 6, lane = t & 63, lrow = lane & 15, g = lane >> 4, lk = g << 3;
  int nw = n0 + wave * 32;
  bf16x8 aK[2][2];
#pragma unroll
  for (int rf = 0; rf < 2; rf++)
#pragma unroll
    for (int ks = 0; ks < 2; ks++)
      aK[rf][ks] = *(const bf16x8*)&Kb[((size_t)bh * NN + nw + rf * 16 + lrow) * DD + ks * 32 + lk];
  f32x4 acc[2][4];
#pragma unroll
  for (int rf = 0; rf < 2; rf++)
#pragma unroll
    for (int lf = 0; lf < 4; lf++) acc[rf][lf] = fzero4();
#pragma unroll
  for (int ks = 0; ks < 2; ks++) {
    bf16x8 bq[4];
#pragma unroll
    for (int lf = 0; lf < 4; lf++)
      bq[lf] = *(const bf16x8*)&Qlm[(lf * 16 + lrow) * 72 + ks * 32 + lk];
#pragma unroll
    for (int rf = 0; rf < 2; rf++)
#pragma unroll
      for (int lf = 0; lf < 4; lf++)
        acc[rf][lf] = __builtin_amdgcn_mfma_f32_16x16x32_bf16(aK[rf][ks], bq[lf], acc[rf][lf], 0, 0, 0);
  }
#pragma unroll
  for (int lf = 0; lf < 4; lf++) {
    float cp = 0.f;
    int l = lf * 16 + lrow;
#pragma unroll
    for (int rf = 0; rf < 2; rf++) {
      U4 p;
#pragma unroll
      for (int i = 0; i < 4; i++) {
        float e = expf(acc[rf][lf][i]);   // logits tiny (sd~0.04): no max needed
        p.s[i] = f2bf(e); cp += e;
      }
      *(unsigned long long*)&Plds[l * 136 + wave * 32 + rf * 16 + g * 4] = p.ll;
    }
    cp += __shfl_xor(cp, 16);
    cp += __shfl_xor(cp, 32);
    if (lane < 16)
      s3part[((bh * 32 + chunk) * 4 + wave) * LL + lf * 16 + lane] = cp;
  }
  __syncthreads();
  f32x4 o2[4];
#pragma unroll
  for (int lf = 0; lf < 4; lf++) o2[lf] = fzero4();
  const int dloc = wave * 16 + lrow;
#pragma unroll
  for (int ks = 0; ks < 4; ++ks) {
    bf16x8 a;
#pragma unroll
    for (int j = 0; j < 8; ++j) a[j] = Vl[(ks * 32 + lk + j) * 68 + dloc];
#pragma unroll
    for (int lf = 0; lf < 4; lf++) {
      bf16x8 b = *(const bf16x8*)&Plds[(lf * 16 + lrow) * 136 + ks * 32 + lk];
      o2[lf] = __builtin_amdgcn_mfma_f32_16x16x32_bf16(a, b, o2[lf], 0, 0, 0);
    }
  }
#pragma unroll
  for (int lf = 0; lf < 4; lf++) {
    int l = lf * 16 + lrow;
#pragma unroll
    for (int i = 0; i < 4; i++) {
      int dd = wave * 16 + g * 4 + i;
      k3VTp[((size_t)chunk * BH + bh) * 4096 + dd * 64 + l] = o2[lf][i];
    }
  }
}

// ---------- per-(b,h): kernel2 softmax + Newton-Schulz inverse + M = inv @ k3V ----------
__device__ __forceinline__ void mm64(const float* X, const float* Y, int row, int c0, float o[8]) {
#pragma unroll
  for (int j = 0; j < 8; j++) o[j] = 0.f;
  for (int k = 0; k < 64; k++) {
    float x = X[row * 68 + k];
    const float4* yp = (const float4*)&Y[k * 68 + c0];
    float4 y0 = yp[0], y1 = yp[1];
    o[0] += x * y0.x; o[1] += x * y0.y; o[2] += x * y0.z; o[3] += x * y0.w;
    o[4] += x * y1.x; o[5] += x * y1.y; o[6] += x * y1.z; o[7] += x * y1.w;
  }
}

__global__ __launch_bounds__(512) void newton_inv(
    const float* __restrict__ QlmF, const float* __restrict__ KlmF,
    const float* __restrict__ k3VTp, const float* __restrict__ s3part,
    short* __restrict__ MTws) {
  __shared__ float A_[64 * 68], B_[64 * 68], C_[64 * 68], D_[64 * 68], E_[64 * 68];
  __shared__ float red[64];
  __shared__ float denom_s;
  int bh = blockIdx.x, t = threadIdx.x;
  int row = t >> 3, c0 = (t & 7) << 3;
#pragma unroll
  for (int i = 0; i < 8; i++) {
    int e = t * 8 + i;
    A_[(e >> 6) * 68 + (e & 63)] = QlmF[bh * 4096 + e];
    B_[(e >> 6) * 68 + (e & 63)] = KlmF[bh * 4096 + e];
  }
  __syncthreads();
  {  // S2 = Qlm @ Klm^T ; softmax rows -> C_
    float4 ar[16];
#pragma unroll
    for (int q = 0; q < 16; q++) ar[q] = *(const float4*)&A_[row * 68 + q * 4];
    float o[8];
#pragma unroll
    for (int mm = 0; mm < 8; mm++) {
      const float4* br = (const float4*)&B_[(c0 + mm) * 68];
      float s = 0.f;
      for (int q = 0; q < 16; q++) {
        float4 b4 = br[q];
        s += ar[q].x * b4.x + ar[q].y * b4.y + ar[q].z * b4.z + ar[q].w * b4.w;
      }
      o[mm] = s;
    }
    float mx = o[0];
#pragma unroll
    for (int mm = 1; mm < 8; mm++) mx = fmaxf(mx, o[mm]);
    mx = fmaxf(mx, __shfl_xor(mx, 1));
    mx = fmaxf(mx, __shfl_xor(mx, 2));
    mx = fmaxf(mx, __shfl_xor(mx, 4));
    float ss = 0.f;
#pragma unroll
    for (int mm = 0; mm < 8; mm++) { o[mm] = expf(o[mm] - mx); ss += o[mm]; }
    ss += __shfl_xor(ss, 1); ss += __shfl_xor(ss, 2); ss += __shfl_xor(ss, 4);
    float r = 1.f / ss;
#pragma unroll
    for (int mm = 0; mm < 8; mm++) C_[row * 68 + c0 + mm] = o[mm] * r;
  }
  __syncthreads();
  if (t < 64) {
    float s = 0.f;
    for (int l2 = 0; l2 < 64; l2++) s += C_[l2 * 68 + t];
    red[t] = s;
  }
  __syncthreads();
  if (t == 0) {
    float m = red[0];
    for (int i = 1; i < 64; i++) m = fmaxf(m, red[i]);
    denom_s = m;
  }
  __syncthreads();
  {
    float rdn = 1.f / denom_s;
#pragma unroll
    for (int i = 0; i < 8; i++) D_[row * 68 + c0 + i] = C_[(c0 + i) * 68 + row] * rdn;
  }
  __syncthreads();
  float* Vc = D_;
  float* t1 = A_;
  float* t2 = B_;
  float* t3 = E_;
  float o[8];
  for (int it = 0; it < 6; it++) {
    mm64(C_, Vc, row, c0, o);                       // KV
#pragma unroll
    for (int j = 0; j < 8; j++) t1[row * 68 + c0 + j] = o[j];
    __syncthreads();
    mm64(t1, t1, row, c0, o);                       // KV@KV
#pragma unroll
    for (int j = 0; j < 8; j++) t2[row * 68 + c0 + j] = 7.f * t1[row * 68 + c0 + j] - o[j];
    __syncthreads();
    mm64(t1, t2, row, c0, o);                       // KV@(7I-KV)
#pragma unroll
    for (int j = 0; j < 8; j++) t3[row * 68 + c0 + j] = 15.f * t1[row * 68 + c0 + j] - o[j];
    __syncthreads();
    mm64(Vc, t3, row, c0, o);                       // V@(13I - T3)
#pragma unroll
    for (int j = 0; j < 8; j++) t2[row * 68 + c0 + j] = 0.25f * (13.f * Vc[row * 68 + c0 + j] - o[j]);
    __syncthreads();
    float* tmp = Vc; Vc = t2; t2 = tmp;
  }
  if (t < 64) {
    float s = 0.f;
    for (int i2 = 0; i2 < 128; i2++) s += s3part[(bh * 128 + i2) * LL + t];
    red[t] = 1.f / s;
  }
  __syncthreads();
#pragma unroll
  for (int i = 0; i < 8; i++) {
    int e = t * 8 + i;
    float s = 0.f;
    for (int c = 0; c < 32; c++) s += k3VTp[((size_t)c * BH + bh) * 4096 + e];
    t1[(e >> 6) * 68 + (e & 63)] = s * red[e & 63];
  }
  __syncthreads();
  {
    float4 ar[16];
#pragma unroll
    for (int q = 0; q < 16; q++) ar[q] = *(const float4*)&t1[row * 68 + q * 4];
    for (int jj = 0; jj < 8; jj++) {
      const float4* dr = (const float4*)&Vc[(c0 + jj) * 68];
      float s = 0.f;
      for (int q = 0; q < 16; q++) {
        float4 d4 = dr[q];
        s += ar[q].x * d4.x + ar[q].y * d4.y + ar[q].z * d4.z + ar[q].w * d4.w;
      }
      MTws[bh * 4096 + row * 64 + c0 + jj] = (short)f2bf(s);
    }
  }
}

// ---------- kernel1 softmax + @M  -> SV (in [B,N,C] bf16) ----------
__global__ __launch_bounds__(256) void pass2(
    const short* __restrict__ Qb, const short* __restrict__ Klmb,
    const short* __restrict__ MTws, short* __restrict__ SVb) {
  int bh = blockIdx.y, n0 = blockIdx.x * 128;
  int bb = bh / HH, hh = bh % HH;
  __shared__ short Klm[64 * 72];
  __shared__ short Mt[64 * 72];
  __shared__ short Pl[128 * 72];
  int t = threadIdx.x;
  for (int r = 0; r < 2; r++) {
    int e = t + r * 256;
    *(bf16x8*)&Klm[(e >> 3) * 72 + (e & 7) * 8] = *(const bf16x8*)&Klmb[bh * 4096 + e * 8];
    *(bf16x8*)&Mt[(e >> 3) * 72 + (e & 7) * 8]  = *(const bf16x8*)&MTws[bh * 4096 + e * 8];
  }
  __syncthreads();
  int wave = t >> 6, lane = t & 63, lrow = lane & 15, lk = (lane >> 4) << 3;
  int nw = wave * 32;
  bf16x8 aQ[2][2];
#pragma unroll
  for (int rf = 0; rf < 2; rf++)
#pragma unroll
    for (int ks = 0; ks < 2; ks++)
      aQ[rf][ks] = *(const bf16x8*)&Qb[((size_t)bh * NN + n0 + nw + rf * 16 + lrow) * DD + ks * 32 + lk];
  f32x4 s[2][4];
#pragma unroll
  for (int rf = 0; rf < 2; rf++)
#pragma unroll
    for (int jf = 0; jf < 4; jf++) s[rf][jf] = fzero4();
#pragma unroll
  for (int ks = 0; ks < 2; ks++) {
    bf16x8 bk[4];
#pragma unroll
    for (int jf = 0; jf < 4; jf++)
      bk[jf] = *(const bf16x8*)&Klm[(jf * 16 + lrow) * 72 + ks * 32 + lk];
#pragma unroll
    for (int rf = 0; rf < 2; rf++)
#pragma unroll
      for (int jf = 0; jf < 4; jf++)
        s[rf][jf] = __builtin_amdgcn_mfma_f32_16x16x32_bf16(aQ[rf][ks], bk[jf], s[rf][jf], 0, 0, 0);
  }
#pragma unroll
  for (int rf = 0; rf < 2; rf++)
#pragma unroll
    for (int i = 0; i < 4; i++) {
      float v0 = s[rf][0][i], v1 = s[rf][1][i], v2 = s[rf][2][i], v3 = s[rf][3][i];
      float mx = fmaxf(fmaxf(v0, v1), fmaxf(v2, v3));
      mx = fmaxf(mx, __shfl_xor(mx, 1));
      mx = fmaxf(mx, __shfl_xor(mx, 2));
      mx = fmaxf(mx, __shfl_xor(mx, 4));
      mx = fmaxf(mx, __shfl_xor(mx, 8));
      v0 = expf(v0 - mx); v1 = expf(v1 - mx); v2 = expf(v2 - mx); v3 = expf(v3 - mx);
      float ss = v0 + v1 + v2 + v3;
      ss += __shfl_xor(ss, 1); ss += __shfl_xor(ss, 2);
      ss += __shfl_xor(ss, 4); ss += __shfl_xor(ss, 8);
      float rr = 1.f / ss;
      int n = nw + rf * 16 + ((lane >> 4) << 2) + i;
      Pl[n * 72 + 0  + lrow] = (short)f2bf(v0 * rr);
      Pl[n * 72 + 16 + lrow] = (short)f2bf(v1 * rr);
      Pl[n * 72 + 32 + lrow] = (short)f2bf(v2 * rr);
      Pl[n * 72 + 48 + lrow] = (short)f2bf(v3 * rr);
    }
  __syncthreads();
  f32x4 o[2][4];
#pragma unroll
  for (int rf = 0; rf < 2; rf++)
#pragma unroll
    for (int df = 0; df < 4; df++) o[rf][df] = fzero4();
#pragma unroll
  for (int ks = 0; ks < 2; ks++) {
    bf16x8 aP[2];
#pragma unroll
    for (int rf = 0; rf < 2; rf++)
      aP[rf] = *(const bf16x8*)&Pl[(nw + rf * 16 + lrow) * 72 + ks * 32 + lk];
    bf16x8 bm[4];
#pragma unroll
    for (int df = 0; df < 4; df++)
      bm[df] = *(const bf16x8*)&Mt[(df * 16 + lrow) * 72 + ks * 32 + lk];
#pragma unroll
    for (int rf = 0; rf < 2; rf++)
#pragma unroll
      for (int df = 0; df < 4; df++)
        o[rf][df] = __builtin_amdgcn_mfma_f32_16x16x32_bf16(aP[rf], bm[df], o[rf][df], 0, 0, 0);
  }
#pragma unroll
  for (int rf = 0; rf < 2; rf++)
#pragma unroll
    for (int df = 0; df < 4; df++)
#pragma unroll
      for (int i = 0; i < 4; i++) {
        int n = n0 + nw + rf * 16 + ((lane >> 4) << 2) + i;
        SVb[((size_t)bb * NN + n) * CC + hh * 64 + df * 16 + lrow] = (short)f2bf(o[rf][df][i]);
      }
}

extern "C" void kernel_launch(void* const* d_in, const int* in_sizes, int n_in,
                              void* d_out, int out_size, void* d_ws, size_t ws_size,
                              hipStream_t stream) {
  const float* x      = (const float*)d_in[0];
  const float* w_qkv  = (const float*)d_in[1];
  const float* w_proj = (const float*)d_in[2];
  const float* b_proj = (const float*)d_in[3];
  float* out = (float*)d_out;

  char* p = (char*)d_ws;
  auto alloc = [&](size_t bytes) -> char* {
    char* r = p; p += (bytes + 255) & ~(size_t)255; return r;
  };
  short* xb     = (short*)alloc((size_t)MM_ * KQKV * 2);
  short* wqkvT  = (short*)alloc((size_t)NQKV * KQKV * 2);
  short* wprojT = (short*)alloc((size_t)CC * CC * 2);
  short* Qb     = (short*)alloc((size_t)BH * NN * DD * 2);
  short* Kb     = (short*)alloc((size_t)BH * NN * DD * 2);
  short* Vb     = (short*)alloc((size_t)BH * NN * DD * 2);
  short* Qlmb   = (short*)alloc((size_t)BH * LL * DD * 2);
  short* Klmb   = (short*)alloc((size_t)BH * LL * DD * 2);
  float* QlmF   = (float*)alloc((size_t)BH * LL * DD * 4);
  float* KlmF   = (float*)alloc((size_t)BH * LL * DD * 4);
  float* s3part = (float*)alloc((size_t)BH * 128 * LL * 4);
  float* k3VTp  = (float*)alloc((size_t)32 * BH * DD * LL * 4);
  short* MTws   = (short*)alloc((size_t)BH * DD * LL * 2);
  short* SVb    = (short*)alloc((size_t)MM_ * CC * 2);

  conv_bf16<<<(MM_ * KQKV / 4 + 255) / 256, 256, 0, stream>>>(x, xb, MM_ * KQKV / 4);
  transpose_bf16<<<dim3(NQKV / 32, KQKV / 32), 256, 0, stream>>>(w_qkv, wqkvT, KQKV, NQKV);
  transpose_bf16<<<dim3(CC / 32, CC / 32), 256, 0, stream>>>(w_proj, wprojT, CC, CC);
  gemm256<0><<<dim3((MM_ / 256) * (NQKV / 256)), 512, 0, stream>>>(
      xb, wqkvT, Qb, Kb, Vb, nullptr, nullptr);
  landmarks<<<dim3(LL, BH), 64, 0, stream>>>(Qb, Kb, Qlmb, Klmb, QlmF, KlmF);
  e12<<<dim3(NN / 128, BH), 256, 0, stream>>>(Kb, Vb, Qlmb, k3VTp, s3part);
  newton_inv<<<BH, 512, 0, stream>>>(QlmF, KlmF, k3VTp, s3part, MTws);
  pass2<<<dim3(NN / 128, BH), 256, 0, stream>>>(Qb, Klmb, MTws, SVb);
  gemm256<1><<<dim3((MM_ / 256) * (CC / 256)), 512, 0, stream>>>(
      SVb, wprojT, nullptr, nullptr, Vb, b_proj, out);
}

// Round 7
// 405.210 us; speedup vs baseline: 1.1559x; 1.1234x over previous
//
#include <hip/hip_runtime.h>
#include <math.h>

// ---------- problem constants ----------
#define BB   8
#define NN   4096
#define CC   768
#define HH   12
#define DD   64
#define LL   64
#define BH   96          // BB*HH
#define MM_  32768       // BB*NN
#define KQKV 768
#define NQKV 2304
#define NTILES 24        // K / 32

typedef short bf16x8 __attribute__((ext_vector_type(8)));
typedef float f32x4  __attribute__((ext_vector_type(4)));

union U4 { unsigned long long ll; unsigned short s[4]; };

__device__ __forceinline__ unsigned short f2bf(float f) {
  union { float f; unsigned u; } v; v.f = f;
  return (unsigned short)((v.u + 0x7FFFu + ((v.u >> 16) & 1u)) >> 16);
}
__device__ __forceinline__ float bf2f(unsigned short h) {
  union { unsigned u; float f; } v; v.u = ((unsigned)h) << 16;
  return v.f;
}
__device__ __forceinline__ f32x4 fzero4() {
  f32x4 z; z[0] = 0.f; z[1] = 0.f; z[2] = 0.f; z[3] = 0.f; return z;
}
__device__ __forceinline__ void gload_lds16(const void* g, void* l) {
  __builtin_amdgcn_global_load_lds(
      (const __attribute__((address_space(1))) void*)g,
      (__attribute__((address_space(3))) void*)l, 16, 0, 0);
}

// ---------- elementwise fp32 -> bf16 ----------
__global__ void conv_bf16(const float* __restrict__ in, short* __restrict__ out, int n4) {
  int i = blockIdx.x * 256 + threadIdx.x;
  if (i >= n4) return;
  float4 v = ((const float4*)in)[i];
  U4 p; p.s[0] = f2bf(v.x); p.s[1] = f2bf(v.y); p.s[2] = f2bf(v.z); p.s[3] = f2bf(v.w);
  ((unsigned long long*)out)[i] = p.ll;
}

// ---------- transpose fp32[R][C] -> bf16[C][R] ----------
__global__ __launch_bounds__(256) void transpose_bf16(
    const float* __restrict__ in, short* __restrict__ out, int R, int C) {
  __shared__ float tile[32][33];
  int c0 = blockIdx.x * 32, r0 = blockIdx.y * 32;
  int tx = threadIdx.x & 31, ty = threadIdx.x >> 5;
  for (int i = ty; i < 32; i += 8)
    tile[i][tx] = in[(r0 + i) * C + c0 + tx];
  __syncthreads();
  for (int i = ty; i < 32; i += 8)
    out[(c0 + i) * R + r0 + tx] = (short)f2bf(tile[tx][i]);
}

// ---------- 128x128 bf16 MFMA GEMM (m97-class), 3-slot ring, 3 blocks/CU ----------
// 256 threads = 4 waves (2Mx2N), per-wave 64x64 output, BK=32, LDS 48 KiB.
// Counted vmcnt(4): tile T+1 landed at each barrier, T+2 in flight (no drain).
// Cross-block overlap (3 blocks/CU) hides per-tile latency chains.
// EPI 0: qkv -> Qb(1/8),Kb,Vb [bh][n][d] + FUSED landmark means (Q/K tiles)
// EPI 1: proj -> fout = acc + bias + V-residual (Vb), 2-pass LDS bounce
template <int EPI>
__global__ __launch_bounds__(256, 3) void gemm128(
    const short* __restrict__ A, const short* __restrict__ Bw,
    short* __restrict__ o0, short* __restrict__ o1, short* __restrict__ o2,
    const float* __restrict__ bias, float* __restrict__ fout,
    short* __restrict__ Qlmb, short* __restrict__ Klmb,
    float* __restrict__ QlmF, float* __restrict__ KlmF) {
  __shared__ short L[24576];   // 48 KiB: slot s at s*16384 B (A 8KB | B 8KB)
  const int t = threadIdx.x;
  const int wave = t >> 6, lane = t & 63;
  const int wr = (wave >> 1) << 6, wc = (wave & 1) << 6;
  const int lrow = lane & 15, g = lane >> 4;

  // XCD-bijective swizzle (grid % 8 == 0: qkv 4608, proj 1536)
  const int q8 = gridDim.x >> 3;
  const int wg = ((int)blockIdx.x & 7) * q8 + ((int)blockIdx.x >> 3);
  const int tm = wg & 255, tn = wg >> 8;
  const int m0 = tm << 7;

  // staging: thread stages 16B slots t and t+256 of each 8KB chunk.
  // LDS slot s holds row s>>2, chunk_pos s&3; element chunk = (s&3)^((s>>2)&3)
  const int csl = (((t & 3) ^ ((t >> 2) & 3)) << 3);
  const short* pA0 = A  + (size_t)(m0 + (t >> 2)) * KQKV + csl;
  const short* pA1 = pA0 + 64 * KQKV;
  const short* pB0 = Bw + (size_t)(tn * 128 + (t >> 2)) * KQKV + csl;
  const short* pB1 = pB0 + 64 * KQKV;
  char* dA = (char*)L + t * 16;          // + slot*16384 ; +4096 for rows 64..127
  char* dB = (char*)L + 8192 + t * 16;

  // frag read: byte = row*64 + ((g ^ (row&3))<<4); row&3 == lrow&3
  const int swz = ((g ^ (lrow & 3)) << 4);
  const int aoff = (wr + lrow) * 64 + swz;           // + rf*1024, + slot*16384
  const int boff = 8192 + (wc + lrow) * 64 + swz;    // + nf*1024

  f32x4 acc[4][4];
#pragma unroll
  for (int i = 0; i < 4; ++i)
#pragma unroll
    for (int j = 0; j < 4; ++j) acc[i][j] = fzero4();

  // prologue: stage tiles 0,1
#pragma unroll
  for (int T = 0; T < 2; ++T) {
    gload_lds16(pA0 + T * 32, dA + T * 16384);
    gload_lds16(pA1 + T * 32, dA + T * 16384 + 4096);
    gload_lds16(pB0 + T * 32, dB + T * 16384);
    gload_lds16(pB1 + T * 32, dB + T * 16384 + 4096);
  }
  asm volatile("s_waitcnt vmcnt(4)" ::: "memory");
  __builtin_amdgcn_s_barrier();

  for (int T = 0; T < NTILES; ++T) {
    const int Ts = T + 2;
    if (Ts < NTILES) {
      const int sb = (Ts % 3) * 16384;
      gload_lds16(pA0 + Ts * 32, dA + sb);
      gload_lds16(pA1 + Ts * 32, dA + sb + 4096);
      gload_lds16(pB0 + Ts * 32, dB + sb);
      gload_lds16(pB1 + Ts * 32, dB + sb + 4096);
    }
    const char* Lb = (const char*)L + (T % 3) * 16384;
    bf16x8 a[4], b[4];
#pragma unroll
    for (int nf = 0; nf < 4; ++nf) b[nf] = *(const bf16x8*)(Lb + boff + nf * 1024);
#pragma unroll
    for (int rf = 0; rf < 4; ++rf) a[rf] = *(const bf16x8*)(Lb + aoff + rf * 1024);
#pragma unroll
    for (int rf = 0; rf < 4; ++rf)
#pragma unroll
      for (int nf = 0; nf < 4; ++nf)
        acc[rf][nf] = __builtin_amdgcn_mfma_f32_16x16x32_bf16(a[rf], b[nf], acc[rf][nf], 0, 0, 0);
    // counted: tile T+1 landed, T+2 stays in flight
    if (T < NTILES - 2)       { asm volatile("s_waitcnt vmcnt(4)" ::: "memory"); }
    else if (T == NTILES - 2) { asm volatile("s_waitcnt vmcnt(0)" ::: "memory"); }
    __builtin_amdgcn_s_barrier();
  }

  // ================= epilogue =================
  if constexpr (EPI == 0) {
    const int cg0 = tn * 128;
    const int three = cg0 / 768;        // 0=Q 1=K 2=V (uniform per block)
    const int ccb = cg0 % 768;
    short* dst = (three == 0) ? o0 : (three == 1) ? o1 : o2;
    const float sc = (three == 0) ? 0.125f : 1.f;
    short* LS = (short*)L;              // [128][136] bf16 = 34.8 KB
#pragma unroll
    for (int rf = 0; rf < 4; ++rf)
#pragma unroll
      for (int nf = 0; nf < 4; ++nf)
#pragma unroll
        for (int i = 0; i < 4; ++i)
          LS[(wr + rf * 16 + g * 4 + i) * 136 + wc + nf * 16 + lrow] =
              (short)f2bf(acc[rf][nf][i] * sc);
    __syncthreads();
#pragma unroll
    for (int k = 0; k < 8; ++k) {
      int id = t + k * 256;
      int row = id >> 4, ch = id & 15;
      bf16x8 v = *(const bf16x8*)&LS[row * 136 + ch * 8];
      int c = ccb + ch * 8, h = c >> 6, d = c & 63;
      int r = m0 + row, bb = r >> 12, n = r & 4095;
      *(bf16x8*)&dst[((size_t)(bb * HH + h) * NN + n) * DD + d] = v;
    }
    // fused landmark means (Q and K tiles only): 2 segs x 128 cols, 1 per thread
    if (three < 2) {
      int seg = t >> 7, col = t & 127;
      float ssum = 0.f;
#pragma unroll
      for (int j = 0; j < 64; ++j) ssum += bf2f((unsigned short)LS[(seg * 64 + j) * 136 + col]);
      ssum *= (1.f / 64.f);
      int l = ((tm & 31) << 1) + seg;
      int c = ccb + col, h = c >> 6, d = c & 63;
      int bh = (tm >> 5) * HH + h;
      int idx = bh * 4096 + l * 64 + d;
      if (three == 0) { QlmF[idx] = ssum; Qlmb[idx] = (short)f2bf(ssum); }
      else            { KlmF[idx] = ssum; Klmb[idx] = (short)f2bf(ssum); }
    }
  } else {
    float* LF = (float*)L;              // [64][132] f32 = 33.8 KB per pass
#pragma unroll
    for (int pass = 0; pass < 2; ++pass) {
      if ((wave >> 1) == pass) {
#pragma unroll
        for (int rf = 0; rf < 4; ++rf)
#pragma unroll
          for (int nf = 0; nf < 4; ++nf)
#pragma unroll
            for (int i = 0; i < 4; ++i)
              LF[(rf * 16 + g * 4 + i) * 132 + wc + nf * 16 + lrow] = acc[rf][nf][i];
      }
      __syncthreads();
#pragma unroll
      for (int k = 0; k < 8; ++k) {
        int id = t + k * 256;
        int row = id >> 5, ch = id & 31;
        float4 v = *(const float4*)&LF[row * 132 + ch * 4];
        int R = m0 + pass * 64 + row;
        int c = tn * 128 + ch * 4;
        int bb = R >> 12, n = R & 4095, h = c >> 6, d = c & 63;
        float4 bi = *(const float4*)&bias[c];
        U4 r4;
        r4.ll = *(const unsigned long long*)&o2[((size_t)(bb * HH + h) * NN + n) * DD + d];
        v.x += bi.x + bf2f(r4.s[0]);
        v.y += bi.y + bf2f(r4.s[1]);
        v.z += bi.z + bf2f(r4.s[2]);
        v.w += bi.w + bf2f(r4.s[3]);
        *(float4*)&fout[(size_t)R * CC + c] = v;
      }
      __syncthreads();
    }
  }
}

// ---------- fused kernel3: per block 512 n-rows in 4 sub-chunks of 128 ----------
// logits+exp in LDS, PV partials accumulated; k3VTp[8][96][4096], s3part[96*32][64]
__global__ __launch_bounds__(256) void e12(
    const short* __restrict__ Kb, const short* __restrict__ Vb,
    const short* __restrict__ Qlmb,
    float* __restrict__ k3VTp, float* __restrict__ s3part) {
  int bh = blockIdx.y, chunk = blockIdx.x;
  __shared__ short Qlm[64 * 72];
  __shared__ short Plds[64 * 136];
  __shared__ short Vl[128 * 68];
  int t = threadIdx.x;
  for (int r = 0; r < 2; r++) {
    int e = t + r * 256;
    *(bf16x8*)&Qlm[(e >> 3) * 72 + (e & 7) * 8] = *(const bf16x8*)&Qlmb[bh * 4096 + e * 8];
  }
  int wave = t >> 6, lane = t & 63, lrow = lane & 15, g = lane >> 4, lk = g << 3;
  f32x4 o2[4];
  float cpl[4];
#pragma unroll
  for (int lf = 0; lf < 4; lf++) { o2[lf] = fzero4(); cpl[lf] = 0.f; }
  const int dloc = wave * 16 + lrow;

  for (int s = 0; s < 4; ++s) {
    int nb = chunk * 512 + s * 128;
    __syncthreads();   // protect Vl/Plds from previous sub-chunk's readers (and Qlm stage, s=0)
#pragma unroll
    for (int r = 0; r < 4; r++) {
      int id = t + r * 256;
      int n = id >> 3, c8 = id & 7;
      unsigned long long v1 = *(const unsigned long long*)&Vb[((size_t)bh * NN + nb + n) * DD + c8 * 8];
      unsigned long long v2 = *(const unsigned long long*)&Vb[((size_t)bh * NN + nb + n) * DD + c8 * 8 + 4];
      *(unsigned long long*)&Vl[n * 68 + c8 * 8] = v1;
      *(unsigned long long*)&Vl[n * 68 + c8 * 8 + 4] = v2;
    }
    int nw = nb + wave * 32;
    bf16x8 aK[2][2];
#pragma unroll
    for (int rf = 0; rf < 2; rf++)
#pragma unroll
      for (int ks = 0; ks < 2; ks++)
        aK[rf][ks] = *(const bf16x8*)&Kb[((size_t)bh * NN + nw + rf * 16 + lrow) * DD + ks * 32 + lk];
    f32x4 acc[2][4];
#pragma unroll
    for (int rf = 0; rf < 2; rf++)
#pragma unroll
      for (int lf = 0; lf < 4; lf++) acc[rf][lf] = fzero4();
#pragma unroll
    for (int ks = 0; ks < 2; ks++) {
      bf16x8 bq[4];
#pragma unroll
      for (int lf = 0; lf < 4; lf++)
        bq[lf] = *(const bf16x8*)&Qlm[(lf * 16 + lrow) * 72 + ks * 32 + lk];
#pragma unroll
      for (int rf = 0; rf < 2; rf++)
#pragma unroll
        for (int lf = 0; lf < 4; lf++)
          acc[rf][lf] = __builtin_amdgcn_mfma_f32_16x16x32_bf16(aK[rf][ks], bq[lf], acc[rf][lf], 0, 0, 0);
    }
#pragma unroll
    for (int lf = 0; lf < 4; lf++) {
      int l = lf * 16 + lrow;
#pragma unroll
      for (int rf = 0; rf < 2; rf++) {
        U4 p;
#pragma unroll
        for (int i = 0; i < 4; i++) {
          float e = expf(acc[rf][lf][i]);   // logits tiny: no max needed
          p.s[i] = f2bf(e); cpl[lf] += e;
        }
        *(unsigned long long*)&Plds[l * 136 + wave * 32 + rf * 16 + g * 4] = p.ll;
      }
    }
    __syncthreads();
    // PV accumulate over this 128-row sub-chunk
#pragma unroll
    for (int ks = 0; ks < 4; ++ks) {
      bf16x8 a;
#pragma unroll
      for (int j = 0; j < 8; ++j) a[j] = Vl[(ks * 32 + lk + j) * 68 + dloc];
#pragma unroll
      for (int lf = 0; lf < 4; lf++) {
        bf16x8 b = *(const bf16x8*)&Plds[(lf * 16 + lrow) * 136 + ks * 32 + lk];
        o2[lf] = __builtin_amdgcn_mfma_f32_16x16x32_bf16(a, b, o2[lf], 0, 0, 0);
      }
    }
  }
#pragma unroll
  for (int lf = 0; lf < 4; lf++) {
    float cp = cpl[lf];
    cp += __shfl_xor(cp, 16);
    cp += __shfl_xor(cp, 32);
    if (lane < 16)
      s3part[((bh * 8 + chunk) * 4 + wave) * LL + lf * 16 + lane] = cp;
    int l = lf * 16 + lrow;
#pragma unroll
    for (int i = 0; i < 4; i++) {
      int dd = wave * 16 + g * 4 + i;
      k3VTp[((size_t)chunk * BH + bh) * 4096 + dd * 64 + l] = o2[lf][i];
    }
  }
}

// ---------- per-(b,h): kernel2 softmax + Newton-Schulz inverse + M = inv @ k3V ----------
__device__ __forceinline__ void mm64(const float* X, const float* Y, int row, int c0, float o[8]) {
#pragma unroll
  for (int j = 0; j < 8; j++) o[j] = 0.f;
  for (int k = 0; k < 64; k++) {
    float x = X[row * 68 + k];
    const float4* yp = (const float4*)&Y[k * 68 + c0];
    float4 y0 = yp[0], y1 = yp[1];
    o[0] += x * y0.x; o[1] += x * y0.y; o[2] += x * y0.z; o[3] += x * y0.w;
    o[4] += x * y1.x; o[5] += x * y1.y; o[6] += x * y1.z; o[7] += x * y1.w;
  }
}

__global__ __launch_bounds__(512) void newton_inv(
    const float* __restrict__ QlmF, const float* __restrict__ KlmF,
    const float* __restrict__ k3VTp, const float* __restrict__ s3part,
    short* __restrict__ MTws) {
  __shared__ float A_[64 * 68], B_[64 * 68], C_[64 * 68], D_[64 * 68], E_[64 * 68];
  __shared__ float red[64];
  __shared__ float denom_s;
  int bh = blockIdx.x, t = threadIdx.x;
  int row = t >> 3, c0 = (t & 7) << 3;
#pragma unroll
  for (int i = 0; i < 8; i++) {
    int e = t * 8 + i;
    A_[(e >> 6) * 68 + (e & 63)] = QlmF[bh * 4096 + e];
    B_[(e >> 6) * 68 + (e & 63)] = KlmF[bh * 4096 + e];
  }
  __syncthreads();
  {  // S2 = Qlm @ Klm^T ; softmax rows -> C_
    float4 ar[16];
#pragma unroll
    for (int q = 0; q < 16; q++) ar[q] = *(const float4*)&A_[row * 68 + q * 4];
    float o[8];
#pragma unroll
    for (int mm = 0; mm < 8; mm++) {
      const float4* br = (const float4*)&B_[(c0 + mm) * 68];
      float s = 0.f;
      for (int q = 0; q < 16; q++) {
        float4 b4 = br[q];
        s += ar[q].x * b4.x + ar[q].y * b4.y + ar[q].z * b4.z + ar[q].w * b4.w;
      }
      o[mm] = s;
    }
    float mx = o[0];
#pragma unroll
    for (int mm = 1; mm < 8; mm++) mx = fmaxf(mx, o[mm]);
    mx = fmaxf(mx, __shfl_xor(mx, 1));
    mx = fmaxf(mx, __shfl_xor(mx, 2));
    mx = fmaxf(mx, __shfl_xor(mx, 4));
    float ss = 0.f;
#pragma unroll
    for (int mm = 0; mm < 8; mm++) { o[mm] = expf(o[mm] - mx); ss += o[mm]; }
    ss += __shfl_xor(ss, 1); ss += __shfl_xor(ss, 2); ss += __shfl_xor(ss, 4);
    float r = 1.f / ss;
#pragma unroll
    for (int mm = 0; mm < 8; mm++) C_[row * 68 + c0 + mm] = o[mm] * r;
  }
  __syncthreads();
  if (t < 64) {
    float s = 0.f;
    for (int l2 = 0; l2 < 64; l2++) s += C_[l2 * 68 + t];
    red[t] = s;
  }
  __syncthreads();
  if (t == 0) {
    float m = red[0];
    for (int i = 1; i < 64; i++) m = fmaxf(m, red[i]);
    denom_s = m;
  }
  __syncthreads();
  {
    float rdn = 1.f / denom_s;
#pragma unroll
    for (int i = 0; i < 8; i++) D_[row * 68 + c0 + i] = C_[(c0 + i) * 68 + row] * rdn;
  }
  __syncthreads();
  float* Vc = D_;
  float* t1 = A_;
  float* t2 = B_;
  float* t3 = E_;
  float o[8];
  for (int it = 0; it < 6; it++) {
    mm64(C_, Vc, row, c0, o);                       // KV
#pragma unroll
    for (int j = 0; j < 8; j++) t1[row * 68 + c0 + j] = o[j];
    __syncthreads();
    mm64(t1, t1, row, c0, o);                       // KV@KV
#pragma unroll
    for (int j = 0; j < 8; j++) t2[row * 68 + c0 + j] = 7.f * t1[row * 68 + c0 + j] - o[j];
    __syncthreads();
    mm64(t1, t2, row, c0, o);                       // KV@(7I-KV)
#pragma unroll
    for (int j = 0; j < 8; j++) t3[row * 68 + c0 + j] = 15.f * t1[row * 68 + c0 + j] - o[j];
    __syncthreads();
    mm64(Vc, t3, row, c0, o);                       // V@(13I - T3)
#pragma unroll
    for (int j = 0; j < 8; j++) t2[row * 68 + c0 + j] = 0.25f * (13.f * Vc[row * 68 + c0 + j] - o[j]);
    __syncthreads();
    float* tmp = Vc; Vc = t2; t2 = tmp;
  }
  if (t < 64) {
    float s = 0.f;
    for (int i2 = 0; i2 < 32; i2++) s += s3part[(bh * 32 + i2) * LL + t];
    red[t] = 1.f / s;
  }
  __syncthreads();
#pragma unroll
  for (int i = 0; i < 8; i++) {
    int e = t * 8 + i;
    float s = 0.f;
#pragma unroll
    for (int c = 0; c < 8; c++) s += k3VTp[((size_t)c * BH + bh) * 4096 + e];
    t1[(e >> 6) * 68 + (e & 63)] = s * red[e & 63];
  }
  __syncthreads();
  {
    float4 ar[16];
#pragma unroll
    for (int q = 0; q < 16; q++) ar[q] = *(const float4*)&t1[row * 68 + q * 4];
    for (int jj = 0; jj < 8; jj++) {
      const float4* dr = (const float4*)&Vc[(c0 + jj) * 68];
      float s = 0.f;
      for (int q = 0; q < 16; q++) {
        float4 d4 = dr[q];
        s += ar[q].x * d4.x + ar[q].y * d4.y + ar[q].z * d4.z + ar[q].w * d4.w;
      }
      MTws[bh * 4096 + row * 64 + c0 + jj] = (short)f2bf(s);
    }
  }
}

// ---------- kernel1 softmax + @M  -> SV (in [B,N,C] bf16) ----------
__global__ __launch_bounds__(256) void pass2(
    const short* __restrict__ Qb, const short* __restrict__ Klmb,
    const short* __restrict__ MTws, short* __restrict__ SVb) {
  int bh = blockIdx.y, n0 = blockIdx.x * 128;
  int bb = bh / HH, hh = bh % HH;
  __shared__ short Klm[64 * 72];
  __shared__ short Mt[64 * 72];
  __shared__ short Pl[128 * 72];
  int t = threadIdx.x;
  for (int r = 0; r < 2; r++) {
    int e = t + r * 256;
    *(bf16x8*)&Klm[(e >> 3) * 72 + (e & 7) * 8] = *(const bf16x8*)&Klmb[bh * 4096 + e * 8];
    *(bf16x8*)&Mt[(e >> 3) * 72 + (e & 7) * 8]  = *(const bf16x8*)&MTws[bh * 4096 + e * 8];
  }
  __syncthreads();
  int wave = t >> 6, lane = t & 63, lrow = lane & 15, lk = (lane >> 4) << 3;
  int nw = wave * 32;
  bf16x8 aQ[2][2];
#pragma unroll
  for (int rf = 0; rf < 2; rf++)
#pragma unroll
    for (int ks = 0; ks < 2; ks++)
      aQ[rf][ks] = *(const bf16x8*)&Qb[((size_t)bh * NN + n0 + nw + rf * 16 + lrow) * DD + ks * 32 + lk];
  f32x4 s[2][4];
#pragma unroll
  for (int rf = 0; rf < 2; rf++)
#pragma unroll
    for (int jf = 0; jf < 4; jf++) s[rf][jf] = fzero4();
#pragma unroll
  for (int ks = 0; ks < 2; ks++) {
    bf16x8 bk[4];
#pragma unroll
    for (int jf = 0; jf < 4; jf++)
      bk[jf] = *(const bf16x8*)&Klm[(jf * 16 + lrow) * 72 + ks * 32 + lk];
#pragma unroll
    for (int rf = 0; rf < 2; rf++)
#pragma unroll
      for (int jf = 0; jf < 4; jf++)
        s[rf][jf] = __builtin_amdgcn_mfma_f32_16x16x32_bf16(aQ[rf][ks], bk[jf], s[rf][jf], 0, 0, 0);
  }
#pragma unroll
  for (int rf = 0; rf < 2; rf++)
#pragma unroll
    for (int i = 0; i < 4; i++) {
      float v0 = s[rf][0][i], v1 = s[rf][1][i], v2 = s[rf][2][i], v3 = s[rf][3][i];
      float mx = fmaxf(fmaxf(v0, v1), fmaxf(v2, v3));
      mx = fmaxf(mx, __shfl_xor(mx, 1));
      mx = fmaxf(mx, __shfl_xor(mx, 2));
      mx = fmaxf(mx, __shfl_xor(mx, 4));
      mx = fmaxf(mx, __shfl_xor(mx, 8));
      v0 = expf(v0 - mx); v1 = expf(v1 - mx); v2 = expf(v2 - mx); v3 = expf(v3 - mx);
      float ss = v0 + v1 + v2 + v3;
      ss += __shfl_xor(ss, 1); ss += __shfl_xor(ss, 2);
      ss += __shfl_xor(ss, 4); ss += __shfl_xor(ss, 8);
      float rr = 1.f / ss;
      int n = nw + rf * 16 + ((lane >> 4) << 2) + i;
      Pl[n * 72 + 0  + lrow] = (short)f2bf(v0 * rr);
      Pl[n * 72 + 16 + lrow] = (short)f2bf(v1 * rr);
      Pl[n * 72 + 32 + lrow] = (short)f2bf(v2 * rr);
      Pl[n * 72 + 48 + lrow] = (short)f2bf(v3 * rr);
    }
  __syncthreads();
  f32x4 o[2][4];
#pragma unroll
  for (int rf = 0; rf < 2; rf++)
#pragma unroll
    for (int df = 0; df < 4; df++) o[rf][df] = fzero4();
#pragma unroll
  for (int ks = 0; ks < 2; ks++) {
    bf16x8 aP[2];
#pragma unroll
    for (int rf = 0; rf < 2; rf++)
      aP[rf] = *(const bf16x8*)&Pl[(nw + rf * 16 + lrow) * 72 + ks * 32 + lk];
    bf16x8 bm[4];
#pragma unroll
    for (int df = 0; df < 4; df++)
      bm[df] = *(const bf16x8*)&Mt[(df * 16 + lrow) * 72 + ks * 32 + lk];
#pragma unroll
    for (int rf = 0; rf < 2; rf++)
#pragma unroll
      for (int df = 0; df < 4; df++)
        o[rf][df] = __builtin_amdgcn_mfma_f32_16x16x32_bf16(aP[rf], bm[df], o[rf][df], 0, 0, 0);
  }
#pragma unroll
  for (int rf = 0; rf < 2; rf++)
#pragma unroll
    for (int df = 0; df < 4; df++)
#pragma unroll
      for (int i = 0; i < 4; i++) {
        int n = n0 + nw + rf * 16 + ((lane >> 4) << 2) + i;
        SVb[((size_t)bb * NN + n) * CC + hh * 64 + df * 16 + lrow] = (short)f2bf(o[rf][df][i]);
      }
}

extern "C" void kernel_launch(void* const* d_in, const int* in_sizes, int n_in,
                              void* d_out, int out_size, void* d_ws, size_t ws_size,
                              hipStream_t stream) {
  const float* x      = (const float*)d_in[0];
  const float* w_qkv  = (const float*)d_in[1];
  const float* w_proj = (const float*)d_in[2];
  const float* b_proj = (const float*)d_in[3];
  float* out = (float*)d_out;

  char* p = (char*)d_ws;
  auto alloc = [&](size_t bytes) -> char* {
    char* r = p; p += (bytes + 255) & ~(size_t)255; return r;
  };
  short* xb     = (short*)alloc((size_t)MM_ * KQKV * 2);
  short* wqkvT  = (short*)alloc((size_t)NQKV * KQKV * 2);
  short* wprojT = (short*)alloc((size_t)CC * CC * 2);
  short* Qb     = (short*)alloc((size_t)BH * NN * DD * 2);
  short* Kb     = (short*)alloc((size_t)BH * NN * DD * 2);
  short* Vb     = (short*)alloc((size_t)BH * NN * DD * 2);
  short* Qlmb   = (short*)alloc((size_t)BH * LL * DD * 2);
  short* Klmb   = (short*)alloc((size_t)BH * LL * DD * 2);
  float* QlmF   = (float*)alloc((size_t)BH * LL * DD * 4);
  float* KlmF   = (float*)alloc((size_t)BH * LL * DD * 4);
  float* s3part = (float*)alloc((size_t)BH * 32 * LL * 4);
  float* k3VTp  = (float*)alloc((size_t)8 * BH * DD * LL * 4);
  short* MTws   = (short*)alloc((size_t)BH * DD * LL * 2);
  short* SVb    = (short*)alloc((size_t)MM_ * CC * 2);

  conv_bf16<<<(MM_ * KQKV / 4 + 255) / 256, 256, 0, stream>>>(x, xb, MM_ * KQKV / 4);
  transpose_bf16<<<dim3(NQKV / 32, KQKV / 32), 256, 0, stream>>>(w_qkv, wqkvT, KQKV, NQKV);
  transpose_bf16<<<dim3(CC / 32, CC / 32), 256, 0, stream>>>(w_proj, wprojT, CC, CC);
  gemm128<0><<<dim3((MM_ / 128) * (NQKV / 128)), 256, 0, stream>>>(
      xb, wqkvT, Qb, Kb, Vb, nullptr, nullptr, Qlmb, Klmb, QlmF, KlmF);
  e12<<<dim3(8, BH), 256, 0, stream>>>(Kb, Vb, Qlmb, k3VTp, s3part);
  newton_inv<<<BH, 512, 0, stream>>>(QlmF, KlmF, k3VTp, s3part, MTws);
  pass2<<<dim3(NN / 128, BH), 256, 0, stream>>>(Qb, Klmb, MTws, SVb);
  gemm128<1><<<dim3((MM_ / 128) * (CC / 128)), 256, 0, stream>>>(
      SVb, wprojT, nullptr, nullptr, Vb, b_proj, out,
      nullptr, nullptr, nullptr, nullptr);
}

// Round 8
// 383.607 us; speedup vs baseline: 1.2210x; 1.0563x over previous
//
#include <hip/hip_runtime.h>
#include <math.h>

// ---------- problem constants ----------
#define BB   8
#define NN   4096
#define CC   768
#define HH   12
#define DD   64
#define LL   64
#define BH   96          // BB*HH
#define MM_  32768       // BB*NN
#define KQKV 768
#define NQKV 2304
#define NTILES 24        // K / 32

typedef short bf16x8 __attribute__((ext_vector_type(8)));
typedef float f32x4  __attribute__((ext_vector_type(4)));

union U4 { unsigned long long ll; unsigned short s[4]; };

__device__ __forceinline__ unsigned short f2bf(float f) {
  union { float f; unsigned u; } v; v.f = f;
  return (unsigned short)((v.u + 0x7FFFu + ((v.u >> 16) & 1u)) >> 16);
}
__device__ __forceinline__ float bf2f(unsigned short h) {
  union { unsigned u; float f; } v; v.u = ((unsigned)h) << 16;
  return v.f;
}
__device__ __forceinline__ f32x4 fzero4() {
  f32x4 z; z[0] = 0.f; z[1] = 0.f; z[2] = 0.f; z[3] = 0.f; return z;
}
__device__ __forceinline__ void gload_lds16(const void* g, void* l) {
  __builtin_amdgcn_global_load_lds(
      (const __attribute__((address_space(1))) void*)g,
      (__attribute__((address_space(3))) void*)l, 16, 0, 0);
}

// ---------- elementwise fp32 -> bf16 ----------
__global__ void conv_bf16(const float* __restrict__ in, short* __restrict__ out, int n4) {
  int i = blockIdx.x * 256 + threadIdx.x;
  if (i >= n4) return;
  float4 v = ((const float4*)in)[i];
  U4 p; p.s[0] = f2bf(v.x); p.s[1] = f2bf(v.y); p.s[2] = f2bf(v.z); p.s[3] = f2bf(v.w);
  ((unsigned long long*)out)[i] = p.ll;
}

// ---------- transpose fp32[R][C] -> bf16[C][R] ----------
__global__ __launch_bounds__(256) void transpose_bf16(
    const float* __restrict__ in, short* __restrict__ out, int R, int C) {
  __shared__ float tile[32][33];
  int c0 = blockIdx.x * 32, r0 = blockIdx.y * 32;
  int tx = threadIdx.x & 31, ty = threadIdx.x >> 5;
  for (int i = ty; i < 32; i += 8)
    tile[i][tx] = in[(r0 + i) * C + c0 + tx];
  __syncthreads();
  for (int i = ty; i < 32; i += 8)
    out[(c0 + i) * R + r0 + tx] = (short)f2bf(tile[tx][i]);
}

// ---------- 128x128 bf16 MFMA GEMM, 3-slot ring, 3 blocks/CU ----------
// 256 threads = 4 waves (2Mx2N), BK=32, LDS 48 KiB, counted vmcnt(4).
// Grid order n-fastest (tn = wg%NT): A-panel stays hot in L2 across 18/6 blocks.
// LDS swizzle f(r)=(r>>1)&3 -> 2-way max bank aliasing (free).
// EPI 0: qkv -> Qb(1/8),Kb,Vb [bh][n][d] + FUSED landmark means
// EPI 1: proj -> fout = acc + bias + V-residual (Vb), 2-pass LDS bounce
template <int EPI>
__global__ __launch_bounds__(256, 3) void gemm128(
    const short* __restrict__ A, const short* __restrict__ Bw,
    short* __restrict__ o0, short* __restrict__ o1, short* __restrict__ o2,
    const float* __restrict__ bias, float* __restrict__ fout,
    short* __restrict__ Qlmb, short* __restrict__ Klmb,
    float* __restrict__ QlmF, float* __restrict__ KlmF) {
  __shared__ short L[24576];   // 48 KiB: slot s at s*16384 B (A 8KB | B 8KB)
  const int t = threadIdx.x;
  const int wave = t >> 6, lane = t & 63;
  const int wr = (wave >> 1) << 6, wc = (wave & 1) << 6;
  const int lrow = lane & 15, g = lane >> 4;

  // XCD-bijective swizzle (grid % 8 == 0: qkv 4608, proj 1536), n-fastest order
  const int q8 = gridDim.x >> 3;
  const int wg = ((int)blockIdx.x & 7) * q8 + ((int)blockIdx.x >> 3);
  const int NT = (EPI == 0) ? 18 : 6;
  const int tn = wg % NT, tm = wg / NT;
  const int m0 = tm << 7;

  // staging: thread t stages 16B LDS slot t (and t+256) of each 8KB chunk.
  // slot s: row r=s>>2, pos p=s&3 holds element chunk p^f(r), f(r)=(r>>1)&3
  const int csl = (((t & 3) ^ ((t >> 3) & 3)) << 3);
  const short* pA0 = A  + (size_t)(m0 + (t >> 2)) * KQKV + csl;
  const short* pA1 = pA0 + 64 * KQKV;
  const short* pB0 = Bw + (size_t)(tn * 128 + (t >> 2)) * KQKV + csl;
  const short* pB1 = pB0 + 64 * KQKV;
  char* dA = (char*)L + t * 16;          // + slot*16384 ; +4096 for rows 64..127
  char* dB = (char*)L + 8192 + t * 16;

  // frag read: byte = row*64 + ((g ^ ((row>>1)&3))<<4); (row>>1)&3 == (lrow>>1)&3
  const int swz = ((g ^ ((lrow >> 1) & 3)) << 4);
  const int aoff = (wr + lrow) * 64 + swz;           // + rf*1024, + slot*16384
  const int boff = 8192 + (wc + lrow) * 64 + swz;    // + nf*1024

  f32x4 acc[4][4];
#pragma unroll
  for (int i = 0; i < 4; ++i)
#pragma unroll
    for (int j = 0; j < 4; ++j) acc[i][j] = fzero4();

  // prologue: stage tiles 0,1
#pragma unroll
  for (int T = 0; T < 2; ++T) {
    gload_lds16(pA0 + T * 32, dA + T * 16384);
    gload_lds16(pA1 + T * 32, dA + T * 16384 + 4096);
    gload_lds16(pB0 + T * 32, dB + T * 16384);
    gload_lds16(pB1 + T * 32, dB + T * 16384 + 4096);
  }
  asm volatile("s_waitcnt vmcnt(4)" ::: "memory");
  __builtin_amdgcn_s_barrier();

  for (int T = 0; T < NTILES; ++T) {
    const int Ts = T + 2;
    if (Ts < NTILES) {
      const int sb = (Ts % 3) * 16384;
      gload_lds16(pA0 + Ts * 32, dA + sb);
      gload_lds16(pA1 + Ts * 32, dA + sb + 4096);
      gload_lds16(pB0 + Ts * 32, dB + sb);
      gload_lds16(pB1 + Ts * 32, dB + sb + 4096);
    }
    const char* Lb = (const char*)L + (T % 3) * 16384;
    bf16x8 a[4], b[4];
#pragma unroll
    for (int nf = 0; nf < 4; ++nf) b[nf] = *(const bf16x8*)(Lb + boff + nf * 1024);
#pragma unroll
    for (int rf = 0; rf < 4; ++rf) a[rf] = *(const bf16x8*)(Lb + aoff + rf * 1024);
#pragma unroll
    for (int rf = 0; rf < 4; ++rf)
#pragma unroll
      for (int nf = 0; nf < 4; ++nf)
        acc[rf][nf] = __builtin_amdgcn_mfma_f32_16x16x32_bf16(a[rf], b[nf], acc[rf][nf], 0, 0, 0);
    // counted: tile T+1 landed, T+2 stays in flight
    if (T < NTILES - 2)       { asm volatile("s_waitcnt vmcnt(4)" ::: "memory"); }
    else if (T == NTILES - 2) { asm volatile("s_waitcnt vmcnt(0)" ::: "memory"); }
    __builtin_amdgcn_s_barrier();
  }

  // ================= epilogue =================
  if constexpr (EPI == 0) {
    const int cg0 = tn * 128;
    const int three = cg0 / 768;        // 0=Q 1=K 2=V (uniform per block)
    const int ccb = cg0 % 768;
    short* dst = (three == 0) ? o0 : (three == 1) ? o1 : o2;
    const float sc = (three == 0) ? 0.125f : 1.f;
    short* LS = (short*)L;              // [128][144] bf16 = 36.9 KB (row shift 8 banks)
#pragma unroll
    for (int rf = 0; rf < 4; ++rf)
#pragma unroll
      for (int nf = 0; nf < 4; ++nf)
#pragma unroll
        for (int i = 0; i < 4; ++i)
          LS[(wr + rf * 16 + g * 4 + i) * 144 + wc + nf * 16 + lrow] =
              (short)f2bf(acc[rf][nf][i] * sc);
    __syncthreads();
#pragma unroll
    for (int k = 0; k < 8; ++k) {
      int id = t + k * 256;
      int row = id >> 4, ch = id & 15;
      bf16x8 v = *(const bf16x8*)&LS[row * 144 + ch * 8];
      int c = ccb + ch * 8, h = c >> 6, d = c & 63;
      int r = m0 + row, bb = r >> 12, n = r & 4095;
      *(bf16x8*)&dst[((size_t)(bb * HH + h) * NN + n) * DD + d] = v;
    }
    // fused landmark means (Q and K tiles only): 2 segs x 128 cols, 1 per thread
    if (three < 2) {
      int seg = t >> 7, col = t & 127;
      float ssum = 0.f;
#pragma unroll
      for (int j = 0; j < 64; ++j) ssum += bf2f((unsigned short)LS[(seg * 64 + j) * 144 + col]);
      ssum *= (1.f / 64.f);
      int l = ((tm & 31) << 1) + seg;
      int c = ccb + col, h = c >> 6, d = c & 63;
      int bh = (tm >> 5) * HH + h;
      int idx = bh * 4096 + l * 64 + d;
      if (three == 0) { QlmF[idx] = ssum; Qlmb[idx] = (short)f2bf(ssum); }
      else            { KlmF[idx] = ssum; Klmb[idx] = (short)f2bf(ssum); }
    }
  } else {
    float* LF = (float*)L;              // [64][136] f32 = 34.8 KB per pass
#pragma unroll
    for (int pass = 0; pass < 2; ++pass) {
      if ((wave >> 1) == pass) {
#pragma unroll
        for (int rf = 0; rf < 4; ++rf)
#pragma unroll
          for (int nf = 0; nf < 4; ++nf)
#pragma unroll
            for (int i = 0; i < 4; ++i)
              LF[(rf * 16 + g * 4 + i) * 136 + wc + nf * 16 + lrow] = acc[rf][nf][i];
      }
      __syncthreads();
#pragma unroll
      for (int k = 0; k < 8; ++k) {
        int id = t + k * 256;
        int row = id >> 5, ch = id & 31;
        float4 v = *(const float4*)&LF[row * 136 + ch * 4];
        int R = m0 + pass * 64 + row;
        int c = tn * 128 + ch * 4;
        int bb = R >> 12, n = R & 4095, h = c >> 6, d = c & 63;
        float4 bi = *(const float4*)&bias[c];
        U4 r4;
        r4.ll = *(const unsigned long long*)&o2[((size_t)(bb * HH + h) * NN + n) * DD + d];
        v.x += bi.x + bf2f(r4.s[0]);
        v.y += bi.y + bf2f(r4.s[1]);
        v.z += bi.z + bf2f(r4.s[2]);
        v.w += bi.w + bf2f(r4.s[3]);
        *(float4*)&fout[(size_t)R * CC + c] = v;
      }
      __syncthreads();
    }
  }
}

// ---------- fused kernel3: per block 512 n-rows in 4 sub-chunks of 128 ----------
__global__ __launch_bounds__(256) void e12(
    const short* __restrict__ Kb, const short* __restrict__ Vb,
    const short* __restrict__ Qlmb,
    float* __restrict__ k3VTp, float* __restrict__ s3part) {
  int bh = blockIdx.y, chunk = blockIdx.x;
  __shared__ short Qlm[64 * 72];
  __shared__ short Plds[64 * 136];
  __shared__ short Vl[128 * 68];
  int t = threadIdx.x;
  for (int r = 0; r < 2; r++) {
    int e = t + r * 256;
    *(bf16x8*)&Qlm[(e >> 3) * 72 + (e & 7) * 8] = *(const bf16x8*)&Qlmb[bh * 4096 + e * 8];
  }
  int wave = t >> 6, lane = t & 63, lrow = lane & 15, g = lane >> 4, lk = g << 3;
  f32x4 o2[4];
  float cpl[4];
#pragma unroll
  for (int lf = 0; lf < 4; lf++) { o2[lf] = fzero4(); cpl[lf] = 0.f; }
  const int dloc = wave * 16 + lrow;

  for (int s = 0; s < 4; ++s) {
    int nb = chunk * 512 + s * 128;
    __syncthreads();
#pragma unroll
    for (int r = 0; r < 4; r++) {
      int id = t + r * 256;
      int n = id >> 3, c8 = id & 7;
      unsigned long long v1 = *(const unsigned long long*)&Vb[((size_t)bh * NN + nb + n) * DD + c8 * 8];
      unsigned long long v2 = *(const unsigned long long*)&Vb[((size_t)bh * NN + nb + n) * DD + c8 * 8 + 4];
      *(unsigned long long*)&Vl[n * 68 + c8 * 8] = v1;
      *(unsigned long long*)&Vl[n * 68 + c8 * 8 + 4] = v2;
    }
    int nw = nb + wave * 32;
    bf16x8 aK[2][2];
#pragma unroll
    for (int rf = 0; rf < 2; rf++)
#pragma unroll
      for (int ks = 0; ks < 2; ks++)
        aK[rf][ks] = *(const bf16x8*)&Kb[((size_t)bh * NN + nw + rf * 16 + lrow) * DD + ks * 32 + lk];
    f32x4 acc[2][4];
#pragma unroll
    for (int rf = 0; rf < 2; rf++)
#pragma unroll
      for (int lf = 0; lf < 4; lf++) acc[rf][lf] = fzero4();
#pragma unroll
    for (int ks = 0; ks < 2; ks++) {
      bf16x8 bq[4];
#pragma unroll
      for (int lf = 0; lf < 4; lf++)
        bq[lf] = *(const bf16x8*)&Qlm[(lf * 16 + lrow) * 72 + ks * 32 + lk];
#pragma unroll
      for (int rf = 0; rf < 2; rf++)
#pragma unroll
        for (int lf = 0; lf < 4; lf++)
          acc[rf][lf] = __builtin_amdgcn_mfma_f32_16x16x32_bf16(aK[rf][ks], bq[lf], acc[rf][lf], 0, 0, 0);
    }
#pragma unroll
    for (int lf = 0; lf < 4; lf++) {
      int l = lf * 16 + lrow;
#pragma unroll
      for (int rf = 0; rf < 2; rf++) {
        U4 p;
#pragma unroll
        for (int i = 0; i < 4; i++) {
          float e = expf(acc[rf][lf][i]);   // logits tiny: no max needed
          p.s[i] = f2bf(e); cpl[lf] += e;
        }
        *(unsigned long long*)&Plds[l * 136 + wave * 32 + rf * 16 + g * 4] = p.ll;
      }
    }
    __syncthreads();
#pragma unroll
    for (int ks = 0; ks < 4; ++ks) {
      bf16x8 a;
#pragma unroll
      for (int j = 0; j < 8; ++j) a[j] = Vl[(ks * 32 + lk + j) * 68 + dloc];
#pragma unroll
      for (int lf = 0; lf < 4; lf++) {
        bf16x8 b = *(const bf16x8*)&Plds[(lf * 16 + lrow) * 136 + ks * 32 + lk];
        o2[lf] = __builtin_amdgcn_mfma_f32_16x16x32_bf16(a, b, o2[lf], 0, 0, 0);
      }
    }
  }
#pragma unroll
  for (int lf = 0; lf < 4; lf++) {
    float cp = cpl[lf];
    cp += __shfl_xor(cp, 16);
    cp += __shfl_xor(cp, 32);
    if (lane < 16)
      s3part[((bh * 8 + chunk) * 4 + wave) * LL + lf * 16 + lane] = cp;
    int l = lf * 16 + lrow;
#pragma unroll
    for (int i = 0; i < 4; i++) {
      int dd = wave * 16 + g * 4 + i;
      k3VTp[((size_t)chunk * BH + bh) * 4096 + dd * 64 + l] = o2[lf][i];
    }
  }
}

// ---------- per-(b,h): kernel2 softmax + Newton-Schulz inverse + M = inv @ k3V ----------
__device__ __forceinline__ void mm64(const float* X, const float* Y, int row, int c0, float o[8]) {
#pragma unroll
  for (int j = 0; j < 8; j++) o[j] = 0.f;
  for (int k = 0; k < 64; k++) {
    float x = X[row * 68 + k];
    const float4* yp = (const float4*)&Y[k * 68 + c0];
    float4 y0 = yp[0], y1 = yp[1];
    o[0] += x * y0.x; o[1] += x * y0.y; o[2] += x * y0.z; o[3] += x * y0.w;
    o[4] += x * y1.x; o[5] += x * y1.y; o[6] += x * y1.z; o[7] += x * y1.w;
  }
}

__global__ __launch_bounds__(512) void newton_inv(
    const float* __restrict__ QlmF, const float* __restrict__ KlmF,
    const float* __restrict__ k3VTp, const float* __restrict__ s3part,
    short* __restrict__ MTws) {
  __shared__ float A_[64 * 68], B_[64 * 68], C_[64 * 68], D_[64 * 68], E_[64 * 68];
  __shared__ float red[64];
  __shared__ float denom_s;
  int bh = blockIdx.x, t = threadIdx.x;
  int row = t >> 3, c0 = (t & 7) << 3;
#pragma unroll
  for (int i = 0; i < 8; i++) {
    int e = t * 8 + i;
    A_[(e >> 6) * 68 + (e & 63)] = QlmF[bh * 4096 + e];
    B_[(e >> 6) * 68 + (e & 63)] = KlmF[bh * 4096 + e];
  }
  __syncthreads();
  {  // S2 = Qlm @ Klm^T ; softmax rows -> C_
    float4 ar[16];
#pragma unroll
    for (int q = 0; q < 16; q++) ar[q] = *(const float4*)&A_[row * 68 + q * 4];
    float o[8];
#pragma unroll
    for (int mm = 0; mm < 8; mm++) {
      const float4* br = (const float4*)&B_[(c0 + mm) * 68];
      float s = 0.f;
      for (int q = 0; q < 16; q++) {
        float4 b4 = br[q];
        s += ar[q].x * b4.x + ar[q].y * b4.y + ar[q].z * b4.z + ar[q].w * b4.w;
      }
      o[mm] = s;
    }
    float mx = o[0];
#pragma unroll
    for (int mm = 1; mm < 8; mm++) mx = fmaxf(mx, o[mm]);
    mx = fmaxf(mx, __shfl_xor(mx, 1));
    mx = fmaxf(mx, __shfl_xor(mx, 2));
    mx = fmaxf(mx, __shfl_xor(mx, 4));
    float ss = 0.f;
#pragma unroll
    for (int mm = 0; mm < 8; mm++) { o[mm] = expf(o[mm] - mx); ss += o[mm]; }
    ss += __shfl_xor(ss, 1); ss += __shfl_xor(ss, 2); ss += __shfl_xor(ss, 4);
    float r = 1.f / ss;
#pragma unroll
    for (int mm = 0; mm < 8; mm++) C_[row * 68 + c0 + mm] = o[mm] * r;
  }
  __syncthreads();
  if (t < 64) {
    float s = 0.f;
    for (int l2 = 0; l2 < 64; l2++) s += C_[l2 * 68 + t];
    red[t] = s;
  }
  __syncthreads();
  if (t == 0) {
    float m = red[0];
    for (int i = 1; i < 64; i++) m = fmaxf(m, red[i]);
    denom_s = m;
  }
  __syncthreads();
  {
    float rdn = 1.f / denom_s;
#pragma unroll
    for (int i = 0; i < 8; i++) D_[row * 68 + c0 + i] = C_[(c0 + i) * 68 + row] * rdn;
  }
  __syncthreads();
  float* Vc = D_;
  float* t1 = A_;
  float* t2 = B_;
  float* t3 = E_;
  float o[8];
  for (int it = 0; it < 6; it++) {
    mm64(C_, Vc, row, c0, o);                       // KV
#pragma unroll
    for (int j = 0; j < 8; j++) t1[row * 68 + c0 + j] = o[j];
    __syncthreads();
    mm64(t1, t1, row, c0, o);                       // KV@KV
#pragma unroll
    for (int j = 0; j < 8; j++) t2[row * 68 + c0 + j] = 7.f * t1[row * 68 + c0 + j] - o[j];
    __syncthreads();
    mm64(t1, t2, row, c0, o);                       // KV@(7I-KV)
#pragma unroll
    for (int j = 0; j < 8; j++) t3[row * 68 + c0 + j] = 15.f * t1[row * 68 + c0 + j] - o[j];
    __syncthreads();
    mm64(Vc, t3, row, c0, o);                       // V@(13I - T3)
#pragma unroll
    for (int j = 0; j < 8; j++) t2[row * 68 + c0 + j] = 0.25f * (13.f * Vc[row * 68 + c0 + j] - o[j]);
    __syncthreads();
    float* tmp = Vc; Vc = t2; t2 = tmp;
  }
  if (t < 64) {
    float s = 0.f;
    for (int i2 = 0; i2 < 32; i2++) s += s3part[(bh * 32 + i2) * LL + t];
    red[t] = 1.f / s;
  }
  __syncthreads();
#pragma unroll
  for (int i = 0; i < 8; i++) {
    int e = t * 8 + i;
    float s = 0.f;
#pragma unroll
    for (int c = 0; c < 8; c++) s += k3VTp[((size_t)c * BH + bh) * 4096 + e];
    t1[(e >> 6) * 68 + (e & 63)] = s * red[e & 63];
  }
  __syncthreads();
  {
    float4 ar[16];
#pragma unroll
    for (int q = 0; q < 16; q++) ar[q] = *(const float4*)&t1[row * 68 + q * 4];
    for (int jj = 0; jj < 8; jj++) {
      const float4* dr = (const float4*)&Vc[(c0 + jj) * 68];
      float s = 0.f;
      for (int q = 0; q < 16; q++) {
        float4 d4 = dr[q];
        s += ar[q].x * d4.x + ar[q].y * d4.y + ar[q].z * d4.z + ar[q].w * d4.w;
      }
      MTws[bh * 4096 + row * 64 + c0 + jj] = (short)f2bf(s);
    }
  }
}

// ---------- kernel1 softmax + @M  -> SV (in [B,N,C] bf16) ----------
__global__ __launch_bounds__(256) void pass2(
    const short* __restrict__ Qb, const short* __restrict__ Klmb,
    const short* __restrict__ MTws, short* __restrict__ SVb) {
  int bh = blockIdx.y, n0 = blockIdx.x * 128;
  int bb = bh / HH, hh = bh % HH;
  __shared__ short Klm[64 * 72];
  __shared__ short Mt[64 * 72];
  __shared__ short Pl[128 * 72];
  int t = threadIdx.x;
  for (int r = 0; r < 2; r++) {
    int e = t + r * 256;
    *(bf16x8*)&Klm[(e >> 3) * 72 + (e & 7) * 8] = *(const bf16x8*)&Klmb[bh * 4096 + e * 8];
    *(bf16x8*)&Mt[(e >> 3) * 72 + (e & 7) * 8]  = *(const bf16x8*)&MTws[bh * 4096 + e * 8];
  }
  __syncthreads();
  int wave = t >> 6, lane = t & 63, lrow = lane & 15, lk = (lane >> 4) << 3;
  int nw = wave * 32;
  bf16x8 aQ[2][2];
#pragma unroll
  for (int rf = 0; rf < 2; rf++)
#pragma unroll
    for (int ks = 0; ks < 2; ks++)
      aQ[rf][ks] = *(const bf16x8*)&Qb[((size_t)bh * NN + n0 + nw + rf * 16 + lrow) * DD + ks * 32 + lk];
  f32x4 s[2][4];
#pragma unroll
  for (int rf = 0; rf < 2; rf++)
#pragma unroll
    for (int jf = 0; jf < 4; jf++) s[rf][jf] = fzero4();
#pragma unroll
  for (int ks = 0; ks < 2; ks++) {
    bf16x8 bk[4];
#pragma unroll
    for (int jf = 0; jf < 4; jf++)
      bk[jf] = *(const bf16x8*)&Klm[(jf * 16 + lrow) * 72 + ks * 32 + lk];
#pragma unroll
    for (int rf = 0; rf < 2; rf++)
#pragma unroll
      for (int jf = 0; jf < 4; jf++)
        s[rf][jf] = __builtin_amdgcn_mfma_f32_16x16x32_bf16(aQ[rf][ks], bk[jf], s[rf][jf], 0, 0, 0);
  }
#pragma unroll
  for (int rf = 0; rf < 2; rf++)
#pragma unroll
    for (int i = 0; i < 4; i++) {
      float v0 = s[rf][0][i], v1 = s[rf][1][i], v2 = s[rf][2][i], v3 = s[rf][3][i];
      float mx = fmaxf(fmaxf(v0, v1), fmaxf(v2, v3));
      mx = fmaxf(mx, __shfl_xor(mx, 1));
      mx = fmaxf(mx, __shfl_xor(mx, 2));
      mx = fmaxf(mx, __shfl_xor(mx, 4));
      mx = fmaxf(mx, __shfl_xor(mx, 8));
      v0 = expf(v0 - mx); v1 = expf(v1 - mx); v2 = expf(v2 - mx); v3 = expf(v3 - mx);
      float ss = v0 + v1 + v2 + v3;
      ss += __shfl_xor(ss, 1); ss += __shfl_xor(ss, 2);
      ss += __shfl_xor(ss, 4); ss += __shfl_xor(ss, 8);
      float rr = 1.f / ss;
      int n = nw + rf * 16 + ((lane >> 4) << 2) + i;
      Pl[n * 72 + 0  + lrow] = (short)f2bf(v0 * rr);
      Pl[n * 72 + 16 + lrow] = (short)f2bf(v1 * rr);
      Pl[n * 72 + 32 + lrow] = (short)f2bf(v2 * rr);
      Pl[n * 72 + 48 + lrow] = (short)f2bf(v3 * rr);
    }
  __syncthreads();
  f32x4 o[2][4];
#pragma unroll
  for (int rf = 0; rf < 2; rf++)
#pragma unroll
    for (int df = 0; df < 4; df++) o[rf][df] = fzero4();
#pragma unroll
  for (int ks = 0; ks < 2; ks++) {
    bf16x8 aP[2];
#pragma unroll
    for (int rf = 0; rf < 2; rf++)
      aP[rf] = *(const bf16x8*)&Pl[(nw + rf * 16 + lrow) * 72 + ks * 32 + lk];
    bf16x8 bm[4];
#pragma unroll
    for (int df = 0; df < 4; df++)
      bm[df] = *(const bf16x8*)&Mt[(df * 16 + lrow) * 72 + ks * 32 + lk];
#pragma unroll
    for (int rf = 0; rf < 2; rf++)
#pragma unroll
      for (int df = 0; df < 4; df++)
        o[rf][df] = __builtin_amdgcn_mfma_f32_16x16x32_bf16(aP[rf], bm[df], o[rf][df], 0, 0, 0);
  }
#pragma unroll
  for (int rf = 0; rf < 2; rf++)
#pragma unroll
    for (int df = 0; df < 4; df++)
#pragma unroll
      for (int i = 0; i < 4; i++) {
        int n = n0 + nw + rf * 16 + ((lane >> 4) << 2) + i;
        SVb[((size_t)bb * NN + n) * CC + hh * 64 + df * 16 + lrow] = (short)f2bf(o[rf][df][i]);
      }
}

extern "C" void kernel_launch(void* const* d_in, const int* in_sizes, int n_in,
                              void* d_out, int out_size, void* d_ws, size_t ws_size,
                              hipStream_t stream) {
  const float* x      = (const float*)d_in[0];
  const float* w_qkv  = (const float*)d_in[1];
  const float* w_proj = (const float*)d_in[2];
  const float* b_proj = (const float*)d_in[3];
  float* out = (float*)d_out;

  char* p = (char*)d_ws;
  auto alloc = [&](size_t bytes) -> char* {
    char* r = p; p += (bytes + 255) & ~(size_t)255; return r;
  };
  short* xb     = (short*)alloc((size_t)MM_ * KQKV * 2);
  short* wqkvT  = (short*)alloc((size_t)NQKV * KQKV * 2);
  short* wprojT = (short*)alloc((size_t)CC * CC * 2);
  short* Qb     = (short*)alloc((size_t)BH * NN * DD * 2);
  short* Kb     = (short*)alloc((size_t)BH * NN * DD * 2);
  short* Vb     = (short*)alloc((size_t)BH * NN * DD * 2);
  short* Qlmb   = (short*)alloc((size_t)BH * LL * DD * 2);
  short* Klmb   = (short*)alloc((size_t)BH * LL * DD * 2);
  float* QlmF   = (float*)alloc((size_t)BH * LL * DD * 4);
  float* KlmF   = (float*)alloc((size_t)BH * LL * DD * 4);
  float* s3part = (float*)alloc((size_t)BH * 32 * LL * 4);
  float* k3VTp  = (float*)alloc((size_t)8 * BH * DD * LL * 4);
  short* MTws   = (short*)alloc((size_t)BH * DD * LL * 2);
  short* SVb    = (short*)alloc((size_t)MM_ * CC * 2);

  conv_bf16<<<(MM_ * KQKV / 4 + 255) / 256, 256, 0, stream>>>(x, xb, MM_ * KQKV / 4);
  transpose_bf16<<<dim3(NQKV / 32, KQKV / 32), 256, 0, stream>>>(w_qkv, wqkvT, KQKV, NQKV);
  transpose_bf16<<<dim3(CC / 32, CC / 32), 256, 0, stream>>>(w_proj, wprojT, CC, CC);
  gemm128<0><<<dim3((MM_ / 128) * (NQKV / 128)), 256, 0, stream>>>(
      xb, wqkvT, Qb, Kb, Vb, nullptr, nullptr, Qlmb, Klmb, QlmF, KlmF);
  e12<<<dim3(8, BH), 256, 0, stream>>>(Kb, Vb, Qlmb, k3VTp, s3part);
  newton_inv<<<BH, 512, 0, stream>>>(QlmF, KlmF, k3VTp, s3part, MTws);
  pass2<<<dim3(NN / 128, BH), 256, 0, stream>>>(Qb, Klmb, MTws, SVb);
  gemm128<1><<<dim3((MM_ / 128) * (CC / 128)), 256, 0, stream>>>(
      SVb, wprojT, nullptr, nullptr, Vb, b_proj, out,
      nullptr, nullptr, nullptr, nullptr);
}

// Round 9
// 376.126 us; speedup vs baseline: 1.2453x; 1.0199x over previous
//
#include <hip/hip_runtime.h>
#include <math.h>

// ---------- problem constants ----------
#define BB   8
#define NN   4096
#define CC   768
#define HH   12
#define DD   64
#define LL   64
#define BH   96          // BB*HH
#define MM_  32768       // BB*NN
#define KQKV 768
#define NQKV 2304
#define NTILES 24        // K / 32

typedef short bf16x8 __attribute__((ext_vector_type(8)));
typedef float f32x4  __attribute__((ext_vector_type(4)));

union U4 { unsigned long long ll; unsigned short s[4]; };

__device__ __forceinline__ unsigned short f2bf(float f) {
  union { float f; unsigned u; } v; v.f = f;
  return (unsigned short)((v.u + 0x7FFFu + ((v.u >> 16) & 1u)) >> 16);
}
__device__ __forceinline__ float bf2f(unsigned short h) {
  union { unsigned u; float f; } v; v.u = ((unsigned)h) << 16;
  return v.f;
}
__device__ __forceinline__ f32x4 fzero4() {
  f32x4 z; z[0] = 0.f; z[1] = 0.f; z[2] = 0.f; z[3] = 0.f; return z;
}
__device__ __forceinline__ void gload_lds16(const void* g, void* l) {
  __builtin_amdgcn_global_load_lds(
      (const __attribute__((address_space(1))) void*)g,
      (__attribute__((address_space(3))) void*)l, 16, 0, 0);
}

// ---------- merged prep: fp32->bf16 convert + both weight transposes ----------
// blocks [0, 24576): conv x -> xb            (256 thr x 1 float4)
// blocks [24576, 26304): transpose w_qkv  (768x2304) -> wqkvT (2304x768)
// blocks [26304, 26880): transpose w_proj (768x768)  -> wprojT (768x768)
__global__ __launch_bounds__(256) void prep(
    const float* __restrict__ x, short* __restrict__ xb,
    const float* __restrict__ w_qkv, short* __restrict__ wqkvT,
    const float* __restrict__ w_proj, short* __restrict__ wprojT) {
  __shared__ float tile[32][33];
  int bid = blockIdx.x;
  if (bid < 24576) {
    int i = bid * 256 + threadIdx.x;
    float4 v = ((const float4*)x)[i];
    U4 p; p.s[0] = f2bf(v.x); p.s[1] = f2bf(v.y); p.s[2] = f2bf(v.z); p.s[3] = f2bf(v.w);
    ((unsigned long long*)xb)[i] = p.ll;
    return;
  }
  const float* in; short* out; int R, C, c0, r0;
  if (bid < 26304) {
    int j = bid - 24576;           // 72 x 24
    in = w_qkv; out = wqkvT; R = KQKV; C = NQKV;
    c0 = (j % 72) * 32; r0 = (j / 72) * 32;
  } else {
    int j = bid - 26304;           // 24 x 24
    in = w_proj; out = wprojT; R = CC; C = CC;
    c0 = (j % 24) * 32; r0 = (j / 24) * 32;
  }
  int tx = threadIdx.x & 31, ty = threadIdx.x >> 5;
  for (int i = ty; i < 32; i += 8)
    tile[i][tx] = in[(r0 + i) * C + c0 + tx];
  __syncthreads();
  for (int i = ty; i < 32; i += 8)
    out[(c0 + i) * R + r0 + tx] = (short)f2bf(tile[tx][i]);
}

// ---------- 128x128 bf16 MFMA GEMM, 3-slot ring, 3 blocks/CU ----------
// 256 threads = 4 waves (2Mx2N), BK=32, LDS 48 KiB, counted vmcnt(4).
// EPI 0 (qkv): tn-PHASED order per XCD (2 phases x 9 tn x 32 tm) so the L2
//   working set (B-half 1.7MB + active A panels ~2MB) fits the 4MB XCD L2.
// EPI 1 (proj): n-fastest (B 1.2MB fits L2; inputs L3-resident).
// LDS swizzle f(r)=(r>>1)&3 -> 2-way max bank aliasing (free).
// EPI 0: qkv -> Qb(1/8),Kb,Vb [bh][n][d] + FUSED landmark means
// EPI 1: proj -> fout = acc + bias + V-residual (Vb), 2-pass LDS bounce
template <int EPI>
__global__ __launch_bounds__(256, 3) void gemm128(
    const short* __restrict__ A, const short* __restrict__ Bw,
    short* __restrict__ o0, short* __restrict__ o1, short* __restrict__ o2,
    const float* __restrict__ bias, float* __restrict__ fout,
    short* __restrict__ Qlmb, short* __restrict__ Klmb,
    float* __restrict__ QlmF, float* __restrict__ KlmF) {
  __shared__ short L[24576];   // 48 KiB: slot s at s*16384 B (A 8KB | B 8KB)
  const int t = threadIdx.x;
  const int wave = t >> 6, lane = t & 63;
  const int wr = (wave >> 1) << 6, wc = (wave & 1) << 6;
  const int lrow = lane & 15, g = lane >> 4;

  // XCD-contiguous mapping: XCD x owns tm range [x*32, x*32+32)
  const int x = (int)blockIdx.x & 7;
  const int local = (int)blockIdx.x >> 3;   // [0, gridDim.x/8)
  int tm, tn;
  if constexpr (EPI == 0) {
    const int phase = local / 288;          // 2 phases x (32 tm x 9 tn)
    const int r = local % 288;
    tm = x * 32 + r / 9;
    tn = phase * 9 + r % 9;
  } else {
    tm = x * 32 + local / 6;                // 32 tm x 6 tn, n-fastest
    tn = local % 6;
  }
  const int m0 = tm << 7;

  // staging: thread t stages 16B LDS slot t (and t+256) of each 8KB chunk.
  // slot s: row r=s>>2, pos p=s&3 holds element chunk p^f(r), f(r)=(r>>1)&3
  const int csl = (((t & 3) ^ ((t >> 3) & 3)) << 3);
  const short* pA0 = A  + (size_t)(m0 + (t >> 2)) * KQKV + csl;
  const short* pA1 = pA0 + 64 * KQKV;
  const short* pB0 = Bw + (size_t)(tn * 128 + (t >> 2)) * KQKV + csl;
  const short* pB1 = pB0 + 64 * KQKV;
  char* dA = (char*)L + t * 16;          // + slot*16384 ; +4096 for rows 64..127
  char* dB = (char*)L + 8192 + t * 16;

  // frag read: byte = row*64 + ((g ^ ((row>>1)&3))<<4); (row>>1)&3 == (lrow>>1)&3
  const int swz = ((g ^ ((lrow >> 1) & 3)) << 4);
  const int aoff = (wr + lrow) * 64 + swz;           // + rf*1024, + slot*16384
  const int boff = 8192 + (wc + lrow) * 64 + swz;    // + nf*1024

  f32x4 acc[4][4];
#pragma unroll
  for (int i = 0; i < 4; ++i)
#pragma unroll
    for (int j = 0; j < 4; ++j) acc[i][j] = fzero4();

  // prologue: stage tiles 0,1
#pragma unroll
  for (int T = 0; T < 2; ++T) {
    gload_lds16(pA0 + T * 32, dA + T * 16384);
    gload_lds16(pA1 + T * 32, dA + T * 16384 + 4096);
    gload_lds16(pB0 + T * 32, dB + T * 16384);
    gload_lds16(pB1 + T * 32, dB + T * 16384 + 4096);
  }
  asm volatile("s_waitcnt vmcnt(4)" ::: "memory");
  __builtin_amdgcn_s_barrier();

  for (int T = 0; T < NTILES; ++T) {
    const int Ts = T + 2;
    if (Ts < NTILES) {
      const int sb = (Ts % 3) * 16384;
      gload_lds16(pA0 + Ts * 32, dA + sb);
      gload_lds16(pA1 + Ts * 32, dA + sb + 4096);
      gload_lds16(pB0 + Ts * 32, dB + sb);
      gload_lds16(pB1 + Ts * 32, dB + sb + 4096);
    }
    const char* Lb = (const char*)L + (T % 3) * 16384;
    bf16x8 a[4], b[4];
#pragma unroll
    for (int nf = 0; nf < 4; ++nf) b[nf] = *(const bf16x8*)(Lb + boff + nf * 1024);
#pragma unroll
    for (int rf = 0; rf < 4; ++rf) a[rf] = *(const bf16x8*)(Lb + aoff + rf * 1024);
#pragma unroll
    for (int rf = 0; rf < 4; ++rf)
#pragma unroll
      for (int nf = 0; nf < 4; ++nf)
        acc[rf][nf] = __builtin_amdgcn_mfma_f32_16x16x32_bf16(a[rf], b[nf], acc[rf][nf], 0, 0, 0);
    // counted: tile T+1 landed, T+2 stays in flight
    if (T < NTILES - 2)       { asm volatile("s_waitcnt vmcnt(4)" ::: "memory"); }
    else if (T == NTILES - 2) { asm volatile("s_waitcnt vmcnt(0)" ::: "memory"); }
    __builtin_amdgcn_s_barrier();
  }

  // ================= epilogue =================
  if constexpr (EPI == 0) {
    const int cg0 = tn * 128;
    const int three = cg0 / 768;        // 0=Q 1=K 2=V (uniform per block)
    const int ccb = cg0 % 768;
    short* dst = (three == 0) ? o0 : (three == 1) ? o1 : o2;
    const float sc = (three == 0) ? 0.125f : 1.f;
    short* LS = (short*)L;              // [128][144] bf16 = 36.9 KB (row shift 8 banks)
#pragma unroll
    for (int rf = 0; rf < 4; ++rf)
#pragma unroll
      for (int nf = 0; nf < 4; ++nf)
#pragma unroll
        for (int i = 0; i < 4; ++i)
          LS[(wr + rf * 16 + g * 4 + i) * 144 + wc + nf * 16 + lrow] =
              (short)f2bf(acc[rf][nf][i] * sc);
    __syncthreads();
#pragma unroll
    for (int k = 0; k < 8; ++k) {
      int id = t + k * 256;
      int row = id >> 4, ch = id & 15;
      bf16x8 v = *(const bf16x8*)&LS[row * 144 + ch * 8];
      int c = ccb + ch * 8, h = c >> 6, d = c & 63;
      int r = m0 + row, bb = r >> 12, n = r & 4095;
      *(bf16x8*)&dst[((size_t)(bb * HH + h) * NN + n) * DD + d] = v;
    }
    // fused landmark means (Q and K tiles only): 2 segs x 128 cols, 1 per thread
    if (three < 2) {
      int seg = t >> 7, col = t & 127;
      float ssum = 0.f;
#pragma unroll
      for (int j = 0; j < 64; ++j) ssum += bf2f((unsigned short)LS[(seg * 64 + j) * 144 + col]);
      ssum *= (1.f / 64.f);
      int l = ((tm & 31) << 1) + seg;
      int c = ccb + col, h = c >> 6, d = c & 63;
      int bh = (tm >> 5) * HH + h;
      int idx = bh * 4096 + l * 64 + d;
      if (three == 0) { QlmF[idx] = ssum; Qlmb[idx] = (short)f2bf(ssum); }
      else            { KlmF[idx] = ssum; Klmb[idx] = (short)f2bf(ssum); }
    }
  } else {
    float* LF = (float*)L;              // [64][136] f32 = 34.8 KB per pass
#pragma unroll
    for (int pass = 0; pass < 2; ++pass) {
      if ((wave >> 1) == pass) {
#pragma unroll
        for (int rf = 0; rf < 4; ++rf)
#pragma unroll
          for (int nf = 0; nf < 4; ++nf)
#pragma unroll
            for (int i = 0; i < 4; ++i)
              LF[(rf * 16 + g * 4 + i) * 136 + wc + nf * 16 + lrow] = acc[rf][nf][i];
      }
      __syncthreads();
#pragma unroll
      for (int k = 0; k < 8; ++k) {
        int id = t + k * 256;
        int row = id >> 5, ch = id & 31;
        float4 v = *(const float4*)&LF[row * 136 + ch * 4];
        int R = m0 + pass * 64 + row;
        int c = tn * 128 + ch * 4;
        int bb = R >> 12, n = R & 4095, h = c >> 6, d = c & 63;
        float4 bi = *(const float4*)&bias[c];
        U4 r4;
        r4.ll = *(const unsigned long long*)&o2[((size_t)(bb * HH + h) * NN + n) * DD + d];
        v.x += bi.x + bf2f(r4.s[0]);
        v.y += bi.y + bf2f(r4.s[1]);
        v.z += bi.z + bf2f(r4.s[2]);
        v.w += bi.w + bf2f(r4.s[3]);
        *(float4*)&fout[(size_t)R * CC + c] = v;
      }
      __syncthreads();
    }
  }
}

// ---------- fused kernel3: per block 512 n-rows in 4 sub-chunks of 128 ----------
__global__ __launch_bounds__(256) void e12(
    const short* __restrict__ Kb, const short* __restrict__ Vb,
    const short* __restrict__ Qlmb,
    float* __restrict__ k3VTp, float* __restrict__ s3part) {
  int bh = blockIdx.y, chunk = blockIdx.x;
  __shared__ short Qlm[64 * 72];
  __shared__ short Plds[64 * 136];
  __shared__ short Vl[128 * 68];
  int t = threadIdx.x;
  for (int r = 0; r < 2; r++) {
    int e = t + r * 256;
    *(bf16x8*)&Qlm[(e >> 3) * 72 + (e & 7) * 8] = *(const bf16x8*)&Qlmb[bh * 4096 + e * 8];
  }
  int wave = t >> 6, lane = t & 63, lrow = lane & 15, g = lane >> 4, lk = g << 3;
  f32x4 o2[4];
  float cpl[4];
#pragma unroll
  for (int lf = 0; lf < 4; lf++) { o2[lf] = fzero4(); cpl[lf] = 0.f; }
  const int dloc = wave * 16 + lrow;

  for (int s = 0; s < 4; ++s) {
    int nb = chunk * 512 + s * 128;
    __syncthreads();
#pragma unroll
    for (int r = 0; r < 4; r++) {
      int id = t + r * 256;
      int n = id >> 3, c8 = id & 7;
      unsigned long long v1 = *(const unsigned long long*)&Vb[((size_t)bh * NN + nb + n) * DD + c8 * 8];
      unsigned long long v2 = *(const unsigned long long*)&Vb[((size_t)bh * NN + nb + n) * DD + c8 * 8 + 4];
      *(unsigned long long*)&Vl[n * 68 + c8 * 8] = v1;
      *(unsigned long long*)&Vl[n * 68 + c8 * 8 + 4] = v2;
    }
    int nw = nb + wave * 32;
    bf16x8 aK[2][2];
#pragma unroll
    for (int rf = 0; rf < 2; rf++)
#pragma unroll
      for (int ks = 0; ks < 2; ks++)
        aK[rf][ks] = *(const bf16x8*)&Kb[((size_t)bh * NN + nw + rf * 16 + lrow) * DD + ks * 32 + lk];
    f32x4 acc[2][4];
#pragma unroll
    for (int rf = 0; rf < 2; rf++)
#pragma unroll
      for (int lf = 0; lf < 4; lf++) acc[rf][lf] = fzero4();
#pragma unroll
    for (int ks = 0; ks < 2; ks++) {
      bf16x8 bq[4];
#pragma unroll
      for (int lf = 0; lf < 4; lf++)
        bq[lf] = *(const bf16x8*)&Qlm[(lf * 16 + lrow) * 72 + ks * 32 + lk];
#pragma unroll
      for (int rf = 0; rf < 2; rf++)
#pragma unroll
        for (int lf = 0; lf < 4; lf++)
          acc[rf][lf] = __builtin_amdgcn_mfma_f32_16x16x32_bf16(aK[rf][ks], bq[lf], acc[rf][lf], 0, 0, 0);
    }
#pragma unroll
    for (int lf = 0; lf < 4; lf++) {
      int l = lf * 16 + lrow;
#pragma unroll
      for (int rf = 0; rf < 2; rf++) {
        U4 p;
#pragma unroll
        for (int i = 0; i < 4; i++) {
          float e = expf(acc[rf][lf][i]);   // logits tiny: no max needed
          p.s[i] = f2bf(e); cpl[lf] += e;
        }
        *(unsigned long long*)&Plds[l * 136 + wave * 32 + rf * 16 + g * 4] = p.ll;
      }
    }
    __syncthreads();
#pragma unroll
    for (int ks = 0; ks < 4; ++ks) {
      bf16x8 a;
#pragma unroll
      for (int j = 0; j < 8; ++j) a[j] = Vl[(ks * 32 + lk + j) * 68 + dloc];
#pragma unroll
      for (int lf = 0; lf < 4; lf++) {
        bf16x8 b = *(const bf16x8*)&Plds[(lf * 16 + lrow) * 136 + ks * 32 + lk];
        o2[lf] = __builtin_amdgcn_mfma_f32_16x16x32_bf16(a, b, o2[lf], 0, 0, 0);
      }
    }
  }
#pragma unroll
  for (int lf = 0; lf < 4; lf++) {
    float cp = cpl[lf];
    cp += __shfl_xor(cp, 16);
    cp += __shfl_xor(cp, 32);
    if (lane < 16)
      s3part[((bh * 8 + chunk) * 4 + wave) * LL + lf * 16 + lane] = cp;
    int l = lf * 16 + lrow;
#pragma unroll
    for (int i = 0; i < 4; i++) {
      int dd = wave * 16 + g * 4 + i;
      k3VTp[((size_t)chunk * BH + bh) * 4096 + dd * 64 + l] = o2[lf][i];
    }
  }
}

// ---------- per-(b,h): kernel2 softmax + Newton-Schulz inverse + M = inv @ k3V ----------
__device__ __forceinline__ void mm64(const float* X, const float* Y, int row, int c0, float o[8]) {
#pragma unroll
  for (int j = 0; j < 8; j++) o[j] = 0.f;
  for (int k = 0; k < 64; k++) {
    float x = X[row * 68 + k];
    const float4* yp = (const float4*)&Y[k * 68 + c0];
    float4 y0 = yp[0], y1 = yp[1];
    o[0] += x * y0.x; o[1] += x * y0.y; o[2] += x * y0.z; o[3] += x * y0.w;
    o[4] += x * y1.x; o[5] += x * y1.y; o[6] += x * y1.z; o[7] += x * y1.w;
  }
}

__global__ __launch_bounds__(512) void newton_inv(
    const float* __restrict__ QlmF, const float* __restrict__ KlmF,
    const float* __restrict__ k3VTp, const float* __restrict__ s3part,
    short* __restrict__ MTws) {
  __shared__ float A_[64 * 68], B_[64 * 68], C_[64 * 68], D_[64 * 68], E_[64 * 68];
  __shared__ float red[64];
  __shared__ float denom_s;
  int bh = blockIdx.x, t = threadIdx.x;
  int row = t >> 3, c0 = (t & 7) << 3;
#pragma unroll
  for (int i = 0; i < 8; i++) {
    int e = t * 8 + i;
    A_[(e >> 6) * 68 + (e & 63)] = QlmF[bh * 4096 + e];
    B_[(e >> 6) * 68 + (e & 63)] = KlmF[bh * 4096 + e];
  }
  __syncthreads();
  {  // S2 = Qlm @ Klm^T ; softmax rows -> C_
    float4 ar[16];
#pragma unroll
    for (int q = 0; q < 16; q++) ar[q] = *(const float4*)&A_[row * 68 + q * 4];
    float o[8];
#pragma unroll
    for (int mm = 0; mm < 8; mm++) {
      const float4* br = (const float4*)&B_[(c0 + mm) * 68];
      float s = 0.f;
      for (int q = 0; q < 16; q++) {
        float4 b4 = br[q];
        s += ar[q].x * b4.x + ar[q].y * b4.y + ar[q].z * b4.z + ar[q].w * b4.w;
      }
      o[mm] = s;
    }
    float mx = o[0];
#pragma unroll
    for (int mm = 1; mm < 8; mm++) mx = fmaxf(mx, o[mm]);
    mx = fmaxf(mx, __shfl_xor(mx, 1));
    mx = fmaxf(mx, __shfl_xor(mx, 2));
    mx = fmaxf(mx, __shfl_xor(mx, 4));
    float ss = 0.f;
#pragma unroll
    for (int mm = 0; mm < 8; mm++) { o[mm] = expf(o[mm] - mx); ss += o[mm]; }
    ss += __shfl_xor(ss, 1); ss += __shfl_xor(ss, 2); ss += __shfl_xor(ss, 4);
    float r = 1.f / ss;
#pragma unroll
    for (int mm = 0; mm < 8; mm++) C_[row * 68 + c0 + mm] = o[mm] * r;
  }
  __syncthreads();
  if (t < 64) {
    float s = 0.f;
    for (int l2 = 0; l2 < 64; l2++) s += C_[l2 * 68 + t];
    red[t] = s;
  }
  __syncthreads();
  if (t == 0) {
    float m = red[0];
    for (int i = 1; i < 64; i++) m = fmaxf(m, red[i]);
    denom_s = m;
  }
  __syncthreads();
  {
    float rdn = 1.f / denom_s;
#pragma unroll
    for (int i = 0; i < 8; i++) D_[row * 68 + c0 + i] = C_[(c0 + i) * 68 + row] * rdn;
  }
  __syncthreads();
  float* Vc = D_;
  float* t1 = A_;
  float* t2 = B_;
  float* t3 = E_;
  float o[8];
  for (int it = 0; it < 6; it++) {
    mm64(C_, Vc, row, c0, o);                       // KV
#pragma unroll
    for (int j = 0; j < 8; j++) t1[row * 68 + c0 + j] = o[j];
    __syncthreads();
    mm64(t1, t1, row, c0, o);                       // KV@KV
#pragma unroll
    for (int j = 0; j < 8; j++) t2[row * 68 + c0 + j] = 7.f * t1[row * 68 + c0 + j] - o[j];
    __syncthreads();
    mm64(t1, t2, row, c0, o);                       // KV@(7I-KV)
#pragma unroll
    for (int j = 0; j < 8; j++) t3[row * 68 + c0 + j] = 15.f * t1[row * 68 + c0 + j] - o[j];
    __syncthreads();
    mm64(Vc, t3, row, c0, o);                       // V@(13I - T3)
#pragma unroll
    for (int j = 0; j < 8; j++) t2[row * 68 + c0 + j] = 0.25f * (13.f * Vc[row * 68 + c0 + j] - o[j]);
    __syncthreads();
    float* tmp = Vc; Vc = t2; t2 = tmp;
  }
  if (t < 64) {
    float s = 0.f;
    for (int i2 = 0; i2 < 32; i2++) s += s3part[(bh * 32 + i2) * LL + t];
    red[t] = 1.f / s;
  }
  __syncthreads();
#pragma unroll
  for (int i = 0; i < 8; i++) {
    int e = t * 8 + i;
    float s = 0.f;
#pragma unroll
    for (int c = 0; c < 8; c++) s += k3VTp[((size_t)c * BH + bh) * 4096 + e];
    t1[(e >> 6) * 68 + (e & 63)] = s * red[e & 63];
  }
  __syncthreads();
  {
    float4 ar[16];
#pragma unroll
    for (int q = 0; q < 16; q++) ar[q] = *(const float4*)&t1[row * 68 + q * 4];
    for (int jj = 0; jj < 8; jj++) {
      const float4* dr = (const float4*)&Vc[(c0 + jj) * 68];
      float s = 0.f;
      for (int q = 0; q < 16; q++) {
        float4 d4 = dr[q];
        s += ar[q].x * d4.x + ar[q].y * d4.y + ar[q].z * d4.z + ar[q].w * d4.w;
      }
      MTws[bh * 4096 + row * 64 + c0 + jj] = (short)f2bf(s);
    }
  }
}

// ---------- kernel1 softmax + @M  -> SV (in [B,N,C] bf16) ----------
__global__ __launch_bounds__(256) void pass2(
    const short* __restrict__ Qb, const short* __restrict__ Klmb,
    const short* __restrict__ MTws, short* __restrict__ SVb) {
  int bh = blockIdx.y, n0 = blockIdx.x * 128;
  int bb = bh / HH, hh = bh % HH;
  __shared__ short Klm[64 * 72];
  __shared__ short Mt[64 * 72];
  __shared__ short Pl[128 * 72];
  int t = threadIdx.x;
  for (int r = 0; r < 2; r++) {
    int e = t + r * 256;
    *(bf16x8*)&Klm[(e >> 3) * 72 + (e & 7) * 8] = *(const bf16x8*)&Klmb[bh * 4096 + e * 8];
    *(bf16x8*)&Mt[(e >> 3) * 72 + (e & 7) * 8]  = *(const bf16x8*)&MTws[bh * 4096 + e * 8];
  }
  __syncthreads();
  int wave = t >> 6, lane = t & 63, lrow = lane & 15, lk = (lane >> 4) << 3;
  int nw = wave * 32;
  bf16x8 aQ[2][2];
#pragma unroll
  for (int rf = 0; rf < 2; rf++)
#pragma unroll
    for (int ks = 0; ks < 2; ks++)
      aQ[rf][ks] = *(const bf16x8*)&Qb[((size_t)bh * NN + n0 + nw + rf * 16 + lrow) * DD + ks * 32 + lk];
  f32x4 s[2][4];
#pragma unroll
  for (int rf = 0; rf < 2; rf++)
#pragma unroll
    for (int jf = 0; jf < 4; jf++) s[rf][jf] = fzero4();
#pragma unroll
  for (int ks = 0; ks < 2; ks++) {
    bf16x8 bk[4];
#pragma unroll
    for (int jf = 0; jf < 4; jf++)
      bk[jf] = *(const bf16x8*)&Klm[(jf * 16 + lrow) * 72 + ks * 32 + lk];
#pragma unroll
    for (int rf = 0; rf < 2; rf++)
#pragma unroll
      for (int jf = 0; jf < 4; jf++)
        s[rf][jf] = __builtin_amdgcn_mfma_f32_16x16x32_bf16(aQ[rf][ks], bk[jf], s[rf][jf], 0, 0, 0);
  }
#pragma unroll
  for (int rf = 0; rf < 2; rf++)
#pragma unroll
    for (int i = 0; i < 4; i++) {
      float v0 = s[rf][0][i], v1 = s[rf][1][i], v2 = s[rf][2][i], v3 = s[rf][3][i];
      float mx = fmaxf(fmaxf(v0, v1), fmaxf(v2, v3));
      mx = fmaxf(mx, __shfl_xor(mx, 1));
      mx = fmaxf(mx, __shfl_xor(mx, 2));
      mx = fmaxf(mx, __shfl_xor(mx, 4));
      mx = fmaxf(mx, __shfl_xor(mx, 8));
      v0 = expf(v0 - mx); v1 = expf(v1 - mx); v2 = expf(v2 - mx); v3 = expf(v3 - mx);
      float ss = v0 + v1 + v2 + v3;
      ss += __shfl_xor(ss, 1); ss += __shfl_xor(ss, 2);
      ss += __shfl_xor(ss, 4); ss += __shfl_xor(ss, 8);
      float rr = 1.f / ss;
      int n = nw + rf * 16 + ((lane >> 4) << 2) + i;
      Pl[n * 72 + 0  + lrow] = (short)f2bf(v0 * rr);
      Pl[n * 72 + 16 + lrow] = (short)f2bf(v1 * rr);
      Pl[n * 72 + 32 + lrow] = (short)f2bf(v2 * rr);
      Pl[n * 72 + 48 + lrow] = (short)f2bf(v3 * rr);
    }
  __syncthreads();
  f32x4 o[2][4];
#pragma unroll
  for (int rf = 0; rf < 2; rf++)
#pragma unroll
    for (int df = 0; df < 4; df++) o[rf][df] = fzero4();
#pragma unroll
  for (int ks = 0; ks < 2; ks++) {
    bf16x8 aP[2];
#pragma unroll
    for (int rf = 0; rf < 2; rf++)
      aP[rf] = *(const bf16x8*)&Pl[(nw + rf * 16 + lrow) * 72 + ks * 32 + lk];
    bf16x8 bm[4];
#pragma unroll
    for (int df = 0; df < 4; df++)
      bm[df] = *(const bf16x8*)&Mt[(df * 16 + lrow) * 72 + ks * 32 + lk];
#pragma unroll
    for (int rf = 0; rf < 2; rf++)
#pragma unroll
      for (int df = 0; df < 4; df++)
        o[rf][df] = __builtin_amdgcn_mfma_f32_16x16x32_bf16(aP[rf], bm[df], o[rf][df], 0, 0, 0);
  }
#pragma unroll
  for (int rf = 0; rf < 2; rf++)
#pragma unroll
    for (int df = 0; df < 4; df++)
#pragma unroll
      for (int i = 0; i < 4; i++) {
        int n = n0 + nw + rf * 16 + ((lane >> 4) << 2) + i;
        SVb[((size_t)bb * NN + n) * CC + hh * 64 + df * 16 + lrow] = (short)f2bf(o[rf][df][i]);
      }
}

extern "C" void kernel_launch(void* const* d_in, const int* in_sizes, int n_in,
                              void* d_out, int out_size, void* d_ws, size_t ws_size,
                              hipStream_t stream) {
  const float* x      = (const float*)d_in[0];
  const float* w_qkv  = (const float*)d_in[1];
  const float* w_proj = (const float*)d_in[2];
  const float* b_proj = (const float*)d_in[3];
  float* out = (float*)d_out;

  char* p = (char*)d_ws;
  auto alloc = [&](size_t bytes) -> char* {
    char* r = p; p += (bytes + 255) & ~(size_t)255; return r;
  };
  short* xb     = (short*)alloc((size_t)MM_ * KQKV * 2);
  short* wqkvT  = (short*)alloc((size_t)NQKV * KQKV * 2);
  short* wprojT = (short*)alloc((size_t)CC * CC * 2);
  short* Qb     = (short*)alloc((size_t)BH * NN * DD * 2);
  short* Kb     = (short*)alloc((size_t)BH * NN * DD * 2);
  short* Vb     = (short*)alloc((size_t)BH * NN * DD * 2);
  short* Qlmb   = (short*)alloc((size_t)BH * LL * DD * 2);
  short* Klmb   = (short*)alloc((size_t)BH * LL * DD * 2);
  float* QlmF   = (float*)alloc((size_t)BH * LL * DD * 4);
  float* KlmF   = (float*)alloc((size_t)BH * LL * DD * 4);
  float* s3part = (float*)alloc((size_t)BH * 32 * LL * 4);
  float* k3VTp  = (float*)alloc((size_t)8 * BH * DD * LL * 4);
  short* MTws   = (short*)alloc((size_t)BH * DD * LL * 2);
  short* SVb    = (short*)alloc((size_t)MM_ * CC * 2);

  prep<<<26880, 256, 0, stream>>>(x, xb, w_qkv, wqkvT, w_proj, wprojT);
  gemm128<0><<<dim3((MM_ / 128) * (NQKV / 128)), 256, 0, stream>>>(
      xb, wqkvT, Qb, Kb, Vb, nullptr, nullptr, Qlmb, Klmb, QlmF, KlmF);
  e12<<<dim3(8, BH), 256, 0, stream>>>(Kb, Vb, Qlmb, k3VTp, s3part);
  newton_inv<<<BH, 512, 0, stream>>>(QlmF, KlmF, k3VTp, s3part, MTws);
  pass2<<<dim3(NN / 128, BH), 256, 0, stream>>>(Qb, Klmb, MTws, SVb);
  gemm128<1><<<dim3((MM_ / 128) * (CC / 128)), 256, 0, stream>>>(
      SVb, wprojT, nullptr, nullptr, Vb, b_proj, out,
      nullptr, nullptr, nullptr, nullptr);
}